// Round 1
// baseline (16420.807 us; speedup 1.0000x reference)
//
#include <hip/hip_runtime.h>

#define TT 2048
#define BB 4
#define DD 512
#define HH 8
#define LL 8
#define FFD 2048
#define VV 256
#define ROWS (BB*TT)

typedef short bf16x8 __attribute__((ext_vector_type(8)));
typedef float f32x4 __attribute__((ext_vector_type(4)));

__device__ __forceinline__ float bf2f(short s){
  union { unsigned u; float f; } x; x.u = ((unsigned)(unsigned short)s) << 16; return x.f;
}
__device__ __forceinline__ short f2bf(float f){
  union { float f; unsigned u; } x; x.f = f;
  unsigned r = (x.u + 0x7fffu + ((x.u >> 16) & 1u)) >> 16;
  return (short)(unsigned short)r;
}

// ---------------- embedding: h[row] = tok_emb[x[row]] + pos_emb[row%T] ----------------
__global__ __launch_bounds__(128) void embed_kernel(const int* __restrict__ x,
    const float* __restrict__ tok, const float* __restrict__ pos, float* __restrict__ h){
  int row = blockIdx.x;
  int t = row & (TT-1);
  int id = x[row];
  const float4 a = *(const float4*)&tok[(size_t)id*DD + threadIdx.x*4];
  const float4 p = *(const float4*)&pos[(size_t)t*DD + threadIdx.x*4];
  float4 r; r.x=a.x+p.x; r.y=a.y+p.y; r.z=a.z+p.z; r.w=a.w+p.w;
  *(float4*)&h[(size_t)row*DD + threadIdx.x*4] = r;
}

// ---------------- LayerNorm (fp32 in, bf16 out) ----------------
__global__ __launch_bounds__(256) void ln_kernel(const float* __restrict__ xx,
    const float* __restrict__ g, const float* __restrict__ bb, short* __restrict__ out){
  __shared__ float sb[4];
  int row = blockIdx.x;
  int i = threadIdx.x*2;
  float2 xv = *(const float2*)&xx[(size_t)row*DD + i];
  int lane = threadIdx.x & 63, w = threadIdx.x >> 6;
  float s = xv.x + xv.y;
  #pragma unroll
  for (int off=32; off; off>>=1) s += __shfl_down(s, off);
  if (lane==0) sb[w] = s;
  __syncthreads();
  float m = (sb[0]+sb[1]+sb[2]+sb[3]) * (1.0f/DD);
  float dx = xv.x - m, dy = xv.y - m;
  float s2 = dx*dx + dy*dy;
  __syncthreads();
  #pragma unroll
  for (int off=32; off; off>>=1) s2 += __shfl_down(s2, off);
  if (lane==0) sb[w] = s2;
  __syncthreads();
  float var = (sb[0]+sb[1]+sb[2]+sb[3]) * (1.0f/DD);
  float rstd = rsqrtf(var + 1e-5f);
  out[(size_t)row*DD + i]   = f2bf(dx*rstd*g[i]   + bb[i]);
  out[(size_t)row*DD + i+1] = f2bf(dy*rstd*g[i+1] + bb[i+1]);
}

// ---------------- weight transpose+cast: src [L][R][C] f32 -> dst [L][C][R] bf16 ----------------
__global__ __launch_bounds__(256) void transpose_cast_kernel(const float* __restrict__ src,
    short* __restrict__ dst, int R, int C){
  __shared__ float tile[32][33];
  size_t off = (size_t)blockIdx.z * R * C;
  src += off; dst += off;
  int c0 = blockIdx.x*32, r0 = blockIdx.y*32;
  int tx = threadIdx.x & 31, ty = threadIdx.x >> 5;
  #pragma unroll
  for (int i=0;i<4;i++) tile[ty + i*8][tx] = src[(size_t)(r0+ty+i*8)*C + c0 + tx];
  __syncthreads();
  #pragma unroll
  for (int i=0;i<4;i++) dst[(size_t)(c0+ty+i*8)*R + r0 + tx] = f2bf(tile[tx][ty+i*8]);
}

// ---------------- plain cast f32 -> bf16 ----------------
__global__ void cast_kernel(const float* __restrict__ in, short* __restrict__ out, int n){
  for (int i = blockIdx.x*blockDim.x + threadIdx.x; i < n; i += gridDim.x*blockDim.x)
    out[i] = f2bf(in[i]);
}

// ---------------- GEMM: C[M][N] = A[M][K] * BT[N][K]^T (+epilogue) ----------------
// EPI: 0 = plain f32 out (no bias); 1 = +bias -> bf16; 2 = +bias,GELU -> bf16; 3 = +bias, residual += into f32
template<int BM, int BN, int EPI>
__global__ __launch_bounds__(256) void gemm_kernel(const short* __restrict__ A,
    const short* __restrict__ BT, const float* __restrict__ bias, void* __restrict__ C,
    int M, int N, int K)
{
  constexpr int FM = BM/32, FN = BN/32;
  __shared__ short As[BM][72];
  __shared__ short Bs[BN][72];
  const int row0 = blockIdx.x*BM, col0 = blockIdx.y*BN;
  const int t = threadIdx.x, lane = t & 63, w = t >> 6;
  const int wm = w >> 1, wn = w & 1;
  const int rr = lane & 15, kg = (lane >> 4)*8;
  f32x4 acc[FM][FN];
  #pragma unroll
  for (int m=0;m<FM;m++)
    #pragma unroll
    for (int n=0;n<FN;n++) acc[m][n] = (f32x4){0.f,0.f,0.f,0.f};

  for (int kt=0; kt<K; kt+=64){
    #pragma unroll
    for (int i=0;i<BM/32;i++){
      int cid = t + i*256; int r = cid >> 3; int c = (cid & 7)*8;
      *(bf16x8*)&As[r][c] = *(const bf16x8*)&A[(size_t)(row0+r)*K + kt + c];
    }
    #pragma unroll
    for (int i=0;i<BN/32;i++){
      int cid = t + i*256; int r = cid >> 3; int c = (cid & 7)*8;
      *(bf16x8*)&Bs[r][c] = *(const bf16x8*)&BT[(size_t)(col0+r)*K + kt + c];
    }
    __syncthreads();
    #pragma unroll
    for (int ks=0; ks<2; ks++){
      bf16x8 af[FM], bfr[FN];
      #pragma unroll
      for (int m=0;m<FM;m++) af[m] = *(const bf16x8*)&As[wm*FM*16 + m*16 + rr][ks*32 + kg];
      #pragma unroll
      for (int n=0;n<FN;n++) bfr[n] = *(const bf16x8*)&Bs[wn*FN*16 + n*16 + rr][ks*32 + kg];
      #pragma unroll
      for (int m=0;m<FM;m++)
        #pragma unroll
        for (int n=0;n<FN;n++)
          acc[m][n] = __builtin_amdgcn_mfma_f32_16x16x32_bf16(af[m], bfr[n], acc[m][n], 0,0,0);
    }
    __syncthreads();
  }
  #pragma unroll
  for (int m=0;m<FM;m++){
    #pragma unroll
    for (int n=0;n<FN;n++){
      int cg = col0 + wn*FN*16 + n*16 + rr;
      float bv = 0.f;
      if constexpr (EPI != 0) bv = bias[cg];
      #pragma unroll
      for (int i=0;i<4;i++){
        int rg = row0 + wm*FM*16 + m*16 + (lane>>4)*4 + i;
        float v = acc[m][n][i] + bv;
        size_t idx = (size_t)rg*N + cg;
        if constexpr (EPI==0) ((float*)C)[idx] = v;
        else if constexpr (EPI==1) ((short*)C)[idx] = f2bf(v);
        else if constexpr (EPI==2) { v = 0.5f*v*(1.0f + erff(v*0.70710678118f)); ((short*)C)[idx] = f2bf(v); }
        else { ((float*)C)[idx] += v; }
      }
    }
  }
}

// ---------------- causal attention, one wave per 64 q-rows of one (b,h) ----------------
__global__ __launch_bounds__(64) void attn_kernel(const short* __restrict__ qkv, short* __restrict__ o){
  __shared__ float Ks[32][65];
  __shared__ float Vs[32][65];
  const int bh = blockIdx.y;
  const int b = bh >> 3, hh = bh & 7;
  const int lane = threadIdx.x;
  const int tq = blockIdx.x*64 + lane;
  const size_t base = (size_t)b*TT*3*DD;
  float q[64];
  {
    const short* qp = qkv + base + (size_t)tq*3*DD + hh*64;
    #pragma unroll
    for (int j=0;j<8;j++){
      bf16x8 v8 = *(const bf16x8*)&qp[j*8];
      #pragma unroll
      for (int e=0;e<8;e++) q[j*8+e] = bf2f(v8[e]);
    }
  }
  float oacc[64];
  #pragma unroll
  for (int d=0;d<64;d++) oacc[d]=0.f;
  float mrun = -1e30f, lrun = 0.f;
  const int nkb = blockIdx.x*2 + 2;
  for (int kb=0; kb<nkb; kb++){
    const int krow = kb*32 + (lane>>1);
    const int cb = (lane&1)*32;
    const short* kp = qkv + base + (size_t)krow*3*DD + DD + hh*64 + cb;
    const short* vp = kp + DD;
    #pragma unroll
    for (int j=0;j<4;j++){
      bf16x8 k8 = *(const bf16x8*)&kp[j*8];
      bf16x8 v8 = *(const bf16x8*)&vp[j*8];
      #pragma unroll
      for (int e=0;e<8;e++){
        Ks[lane>>1][cb + j*8 + e] = bf2f(k8[e]);
        Vs[lane>>1][cb + j*8 + e] = bf2f(v8[e]);
      }
    }
    __syncthreads();
    const int kmax = tq - kb*32;
    for (int kk=0; kk<32; kk++){
      float s0=0.f,s1=0.f,s2=0.f,s3=0.f;
      #pragma unroll
      for (int d=0; d<64; d+=4){
        s0 += q[d+0]*Ks[kk][d+0];
        s1 += q[d+1]*Ks[kk][d+1];
        s2 += q[d+2]*Ks[kk][d+2];
        s3 += q[d+3]*Ks[kk][d+3];
      }
      float s = ((s0+s1)+(s2+s3)) * 0.125f;
      if (kk <= kmax){
        if (s <= mrun){
          float pp = __expf(s - mrun);
          lrun += pp;
          #pragma unroll
          for (int d=0;d<64;d++) oacc[d] += pp*Vs[kk][d];
        } else {
          float corr = __expf(mrun - s);
          mrun = s;
          lrun = lrun*corr + 1.f;
          #pragma unroll
          for (int d=0;d<64;d++) oacc[d] = oacc[d]*corr + Vs[kk][d];
        }
      }
    }
    __syncthreads();
  }
  const float inv = 1.f/lrun;
  short* op = o + ((size_t)b*TT + tq)*DD + hh*64;
  #pragma unroll
  for (int d=0;d<64;d++) op[d] = f2bf(oacc[d]*inv);
}

extern "C" void kernel_launch(void* const* d_in, const int* in_sizes, int n_in,
                              void* d_out, int out_size, void* d_ws, size_t ws_size,
                              hipStream_t stream) {
  const int*   x      = (const int*)d_in[0];
  const float* tok    = (const float*)d_in[1];
  const float* pos    = (const float*)d_in[2];
  const float* attn_w = (const float*)d_in[3];
  const float* attn_b = (const float*)d_in[4];
  const float* proj_w = (const float*)d_in[5];
  const float* proj_b = (const float*)d_in[6];
  const float* ln1_g  = (const float*)d_in[7];
  const float* ln1_b  = (const float*)d_in[8];
  const float* ln2_g  = (const float*)d_in[9];
  const float* ln2_b  = (const float*)d_in[10];
  const float* ff1_w  = (const float*)d_in[11];
  const float* ff1_b  = (const float*)d_in[12];
  const float* ff2_w  = (const float*)d_in[13];
  const float* ff2_b  = (const float*)d_in[14];
  const float* lnf_g  = (const float*)d_in[15];
  const float* lnf_b  = (const float*)d_in[16];

  char* p = (char*)d_ws;
  float* h   = (float*)p; p += (size_t)ROWS*DD*4;
  short* hn  = (short*)p; p += (size_t)ROWS*DD*2;
  short* qkv = (short*)p; p += (size_t)ROWS*3*DD*2;
  short* ob  = (short*)p; p += (size_t)ROWS*DD*2;
  short* ffb = (short*)p; p += (size_t)ROWS*FFD*2;
  short* awT = (short*)p; p += (size_t)LL*3*DD*DD*2;
  short* pwT = (short*)p; p += (size_t)LL*DD*DD*2;
  short* f1T = (short*)p; p += (size_t)LL*FFD*DD*2;
  short* f2T = (short*)p; p += (size_t)LL*DD*FFD*2;
  short* lmT = (short*)p; p += (size_t)VV*DD*2;

  transpose_cast_kernel<<<dim3(48,16,8),256,0,stream>>>(attn_w, awT, DD, 3*DD);
  transpose_cast_kernel<<<dim3(16,16,8),256,0,stream>>>(proj_w, pwT, DD, DD);
  transpose_cast_kernel<<<dim3(64,16,8),256,0,stream>>>(ff1_w, f1T, DD, FFD);
  transpose_cast_kernel<<<dim3(16,64,8),256,0,stream>>>(ff2_w, f2T, FFD, DD);
  cast_kernel<<<128,256,0,stream>>>(tok, lmT, VV*DD);
  embed_kernel<<<ROWS,128,0,stream>>>(x, tok, pos, h);

  for (int l=0;l<LL;l++){
    ln_kernel<<<ROWS,256,0,stream>>>(h, ln1_g + l*DD, ln1_b + l*DD, hn);
    gemm_kernel<128,128,1><<<dim3(ROWS/128, (3*DD)/128),256,0,stream>>>(
        hn, awT + (size_t)l*3*DD*DD, attn_b + (size_t)l*3*DD, qkv, ROWS, 3*DD, DD);
    attn_kernel<<<dim3(TT/64, BB*HH),64,0,stream>>>(qkv, ob);
    gemm_kernel<128,128,3><<<dim3(ROWS/128, DD/128),256,0,stream>>>(
        ob, pwT + (size_t)l*DD*DD, proj_b + (size_t)l*DD, h, ROWS, DD, DD);
    ln_kernel<<<ROWS,256,0,stream>>>(h, ln2_g + l*DD, ln2_b + l*DD, hn);
    gemm_kernel<128,128,2><<<dim3(ROWS/128, FFD/128),256,0,stream>>>(
        hn, f1T + (size_t)l*FFD*DD, ff1_b + (size_t)l*FFD, ffb, ROWS, FFD, DD);
    gemm_kernel<128,128,3><<<dim3(ROWS/128, DD/128),256,0,stream>>>(
        ffb, f2T + (size_t)l*DD*FFD, ff2_b + (size_t)l*DD, h, ROWS, DD, FFD);
  }
  ln_kernel<<<ROWS,256,0,stream>>>(h, lnf_g, lnf_b, hn);
  gemm_kernel<64,64,0><<<dim3(ROWS/64, VV/64),256,0,stream>>>(
      hn, lmT, nullptr, d_out, ROWS, VV, DD);
}

// Round 2
// 2148.808 us; speedup vs baseline: 7.6418x; 7.6418x over previous
//
#include <hip/hip_runtime.h>

#define TT 2048
#define BB 4
#define DD 512
#define HH 8
#define LL 8
#define FFD 2048
#define VV 256
#define ROWS (BB*TT)

typedef short bf16x8 __attribute__((ext_vector_type(8)));
typedef float f32x4 __attribute__((ext_vector_type(4)));

__device__ __forceinline__ float bf2f(short s){
  union { unsigned u; float f; } x; x.u = ((unsigned)(unsigned short)s) << 16; return x.f;
}
__device__ __forceinline__ short f2bf(float f){
  union { float f; unsigned u; } x; x.f = f;
  unsigned r = (x.u + 0x7fffu + ((x.u >> 16) & 1u)) >> 16;
  return (short)(unsigned short)r;
}
__device__ __forceinline__ unsigned pack2(float lo, float hi){
  return (unsigned)(unsigned short)f2bf(lo) | ((unsigned)(unsigned short)f2bf(hi) << 16);
}

// ---------------- embedding: h[row] = tok_emb[x[row]] + pos_emb[row%T] ----------------
__global__ __launch_bounds__(128) void embed_kernel(const int* __restrict__ x,
    const float* __restrict__ tok, const float* __restrict__ pos, float* __restrict__ h){
  int row = blockIdx.x;
  int t = row & (TT-1);
  int id = x[row];
  const float4 a = *(const float4*)&tok[(size_t)id*DD + threadIdx.x*4];
  const float4 p = *(const float4*)&pos[(size_t)t*DD + threadIdx.x*4];
  float4 r; r.x=a.x+p.x; r.y=a.y+p.y; r.z=a.z+p.z; r.w=a.w+p.w;
  *(float4*)&h[(size_t)row*DD + threadIdx.x*4] = r;
}

// ---------------- LayerNorm (fp32 in, bf16 out) ----------------
__global__ __launch_bounds__(256) void ln_kernel(const float* __restrict__ xx,
    const float* __restrict__ g, const float* __restrict__ bb, short* __restrict__ out){
  __shared__ float sb[4];
  int row = blockIdx.x;
  int i = threadIdx.x*2;
  float2 xv = *(const float2*)&xx[(size_t)row*DD + i];
  int lane = threadIdx.x & 63, w = threadIdx.x >> 6;
  float s = xv.x + xv.y;
  #pragma unroll
  for (int off=32; off; off>>=1) s += __shfl_down(s, off);
  if (lane==0) sb[w] = s;
  __syncthreads();
  float m = (sb[0]+sb[1]+sb[2]+sb[3]) * (1.0f/DD);
  float dx = xv.x - m, dy = xv.y - m;
  float s2 = dx*dx + dy*dy;
  __syncthreads();
  #pragma unroll
  for (int off=32; off; off>>=1) s2 += __shfl_down(s2, off);
  if (lane==0) sb[w] = s2;
  __syncthreads();
  float var = (sb[0]+sb[1]+sb[2]+sb[3]) * (1.0f/DD);
  float rstd = rsqrtf(var + 1e-5f);
  out[(size_t)row*DD + i]   = f2bf(dx*rstd*g[i]   + bb[i]);
  out[(size_t)row*DD + i+1] = f2bf(dy*rstd*g[i+1] + bb[i+1]);
}

// ---------------- weight transpose+cast: src [L][R][C] f32 -> dst [L][C][R] bf16 ----------------
__global__ __launch_bounds__(256) void transpose_cast_kernel(const float* __restrict__ src,
    short* __restrict__ dst, int R, int C){
  __shared__ float tile[32][33];
  size_t off = (size_t)blockIdx.z * R * C;
  src += off; dst += off;
  int c0 = blockIdx.x*32, r0 = blockIdx.y*32;
  int tx = threadIdx.x & 31, ty = threadIdx.x >> 5;
  #pragma unroll
  for (int i=0;i<4;i++) tile[ty + i*8][tx] = src[(size_t)(r0+ty+i*8)*C + c0 + tx];
  __syncthreads();
  #pragma unroll
  for (int i=0;i<4;i++) dst[(size_t)(c0+ty+i*8)*R + r0 + tx] = f2bf(tile[tx][ty+i*8]);
}

// ---------------- plain cast f32 -> bf16 ----------------
__global__ void cast_kernel(const float* __restrict__ in, short* __restrict__ out, int n){
  for (int i = blockIdx.x*blockDim.x + threadIdx.x; i < n; i += gridDim.x*blockDim.x)
    out[i] = f2bf(in[i]);
}

// ---------------- GEMM: C[M][N] = A[M][K] * BT[N][K]^T (+epilogue) ----------------
// EPI: 0 = plain f32 out (no bias); 1 = +bias -> bf16; 2 = +bias,GELU -> bf16; 3 = +bias, residual += into f32
template<int BM, int BN, int EPI>
__global__ __launch_bounds__(256) void gemm_kernel(const short* __restrict__ A,
    const short* __restrict__ BT, const float* __restrict__ bias, void* __restrict__ C,
    int M, int N, int K)
{
  constexpr int FM = BM/32, FN = BN/32;
  __shared__ short As[BM][72];
  __shared__ short Bs[BN][72];
  const int row0 = blockIdx.x*BM, col0 = blockIdx.y*BN;
  const int t = threadIdx.x, lane = t & 63, w = t >> 6;
  const int wm = w >> 1, wn = w & 1;
  const int rr = lane & 15, kg = (lane >> 4)*8;
  f32x4 acc[FM][FN];
  #pragma unroll
  for (int m=0;m<FM;m++)
    #pragma unroll
    for (int n=0;n<FN;n++) acc[m][n] = (f32x4){0.f,0.f,0.f,0.f};

  for (int kt=0; kt<K; kt+=64){
    #pragma unroll
    for (int i=0;i<BM/32;i++){
      int cid = t + i*256; int r = cid >> 3; int c = (cid & 7)*8;
      *(bf16x8*)&As[r][c] = *(const bf16x8*)&A[(size_t)(row0+r)*K + kt + c];
    }
    #pragma unroll
    for (int i=0;i<BN/32;i++){
      int cid = t + i*256; int r = cid >> 3; int c = (cid & 7)*8;
      *(bf16x8*)&Bs[r][c] = *(const bf16x8*)&BT[(size_t)(col0+r)*K + kt + c];
    }
    __syncthreads();
    #pragma unroll
    for (int ks=0; ks<2; ks++){
      bf16x8 af[FM], bfr[FN];
      #pragma unroll
      for (int m=0;m<FM;m++) af[m] = *(const bf16x8*)&As[wm*FM*16 + m*16 + rr][ks*32 + kg];
      #pragma unroll
      for (int n=0;n<FN;n++) bfr[n] = *(const bf16x8*)&Bs[wn*FN*16 + n*16 + rr][ks*32 + kg];
      #pragma unroll
      for (int m=0;m<FM;m++)
        #pragma unroll
        for (int n=0;n<FN;n++)
          acc[m][n] = __builtin_amdgcn_mfma_f32_16x16x32_bf16(af[m], bfr[n], acc[m][n], 0,0,0);
    }
    __syncthreads();
  }
  #pragma unroll
  for (int m=0;m<FM;m++){
    #pragma unroll
    for (int n=0;n<FN;n++){
      int cg = col0 + wn*FN*16 + n*16 + rr;
      float bv = 0.f;
      if constexpr (EPI != 0) bv = bias[cg];
      #pragma unroll
      for (int i=0;i<4;i++){
        int rg = row0 + wm*FM*16 + m*16 + (lane>>4)*4 + i;
        float v = acc[m][n][i] + bv;
        size_t idx = (size_t)rg*N + cg;
        if constexpr (EPI==0) ((float*)C)[idx] = v;
        else if constexpr (EPI==1) ((short*)C)[idx] = f2bf(v);
        else if constexpr (EPI==2) { v = 0.5f*v*(1.0f + erff(v*0.70710678118f)); ((short*)C)[idx] = f2bf(v); }
        else { ((float*)C)[idx] += v; }
      }
    }
  }
}

// ---------------- MFMA flash attention ----------------
// grid (T/64, B*H), 256 threads = 4 waves; wave owns 16 q-rows.
// S^T = mfma(A=K, B=Q): lane holds q=lane&15 (one q), keys=(lane>>4)*4+i+16f.
// O^T = mfma(A=V^T (strided reads from row-major V), B=P^T (shuffled)).
__global__ __launch_bounds__(256) void attn_kernel(const short* __restrict__ qkv, short* __restrict__ o){
  __shared__ short Ks[64][72];
  __shared__ short Vs[64][68];
  __shared__ float Osh[64][65];
  const int b = blockIdx.y >> 3, hh = blockIdx.y & 7;
  const int qb = gridDim.x - 1 - blockIdx.x;   // heavy blocks first
  const int q0 = qb * 64;
  const int t = threadIdx.x, lane = t & 63, wid = t >> 6;
  const int g = lane >> 4, qi = lane & 15;
  const int qg = q0 + wid*16 + qi;             // this lane's global q row
  const size_t base = (size_t)b*TT*3*DD + hh*64;

  bf16x8 qreg[2];
  {
    const short* qp = qkv + base + (size_t)qg*3*DD + g*8;
    qreg[0] = *(const bf16x8*)&qp[0];
    qreg[1] = *(const bf16x8*)&qp[32];
  }
  f32x4 oacc[4];
  #pragma unroll
  for (int mf=0; mf<4; mf++) oacc[mf] = (f32x4){0.f,0.f,0.f,0.f};
  float mrun = -1e30f, lrun = 0.f;

  const int kr = t >> 2, c0 = (t & 3) * 16;
  const int ntiles = qb + 1;
  for (int kb = 0; kb < ntiles; kb++){
    // ---- stage K[64][64] and V[64][64] (issue loads before barrier) ----
    const short* kp = qkv + base + (size_t)(kb*64 + kr)*3*DD + DD + c0;
    bf16x8 k0 = *(const bf16x8*)&kp[0];
    bf16x8 k1 = *(const bf16x8*)&kp[8];
    bf16x8 v0 = *(const bf16x8*)&kp[DD];
    bf16x8 v1 = *(const bf16x8*)&kp[DD+8];
    __syncthreads();
    *(bf16x8*)&Ks[kr][c0]   = k0;
    *(bf16x8*)&Ks[kr][c0+8] = k1;
    { short4* d0 = (short4*)&Vs[kr][c0];
      d0[0] = ((short4*)&v0)[0]; d0[1] = ((short4*)&v0)[1];
      short4* d1 = (short4*)&Vs[kr][c0+8];
      d1[0] = ((short4*)&v1)[0]; d1[1] = ((short4*)&v1)[1]; }
    __syncthreads();

    // ---- S^T = K * Q^T  (4 key-frags x 2 k-steps) ----
    f32x4 sacc[4];
    #pragma unroll
    for (int f=0; f<4; f++) sacc[f] = (f32x4){0.f,0.f,0.f,0.f};
    #pragma unroll
    for (int ks=0; ks<2; ks++){
      #pragma unroll
      for (int f=0; f<4; f++){
        bf16x8 kf = *(const bf16x8*)&Ks[f*16 + qi][ks*32 + g*8];
        sacc[f] = __builtin_amdgcn_mfma_f32_16x16x32_bf16(kf, qreg[ks], sacc[f], 0,0,0);
      }
    }

    // ---- mask + online softmax (per-lane: one q, 16 keys) ----
    float p[4][4];
    float tm = -1e30f;
    #pragma unroll
    for (int f=0; f<4; f++)
      #pragma unroll
      for (int i=0; i<4; i++){
        int kgk = kb*64 + f*16 + g*4 + i;
        float s = sacc[f][i] * 0.125f;
        s = (kgk <= qg) ? s : -1e30f;
        p[f][i] = s;
        tm = fmaxf(tm, s);
      }
    tm = fmaxf(tm, __shfl_xor(tm, 16));
    tm = fmaxf(tm, __shfl_xor(tm, 32));
    float mnew = fmaxf(mrun, tm);
    float corr = __expf(mrun - mnew);
    float ts = 0.f;
    #pragma unroll
    for (int f=0; f<4; f++)
      #pragma unroll
      for (int i=0; i<4; i++){
        float e = __expf(p[f][i] - mnew);
        p[f][i] = e;
        ts += e;
      }
    ts += __shfl_xor(ts, 16);
    ts += __shfl_xor(ts, 32);
    lrun = lrun * corr + ts;
    mrun = mnew;
    #pragma unroll
    for (int mf=0; mf<4; mf++)
      #pragma unroll
      for (int i=0; i<4; i++) oacc[mf][i] *= corr;

    // ---- pack P to bf16 pairs: pk[f][h] = keys (16f+4g+2h, +1) for q=qi ----
    unsigned pk[4][2];
    #pragma unroll
    for (int f=0; f<4; f++){
      pk[f][0] = pack2(p[f][0], p[f][1]);
      pk[f][1] = pack2(p[f][2], p[f][3]);
    }
    const int srcA = ((g & 1) << 5) + qi;
    const int srcB = srcA + 16;
    const bool hi = (g >> 1) != 0;
    #pragma unroll
    for (int w=0; w<2; w++){
      // B-frag (P^T): dest group g needs keys 32w+8g..+7 for its q
      unsigned a0 = (unsigned)__shfl((int)pk[2*w  ][0], srcA);
      unsigned a1 = (unsigned)__shfl((int)pk[2*w  ][1], srcA);
      unsigned a2 = (unsigned)__shfl((int)pk[2*w  ][0], srcB);
      unsigned a3 = (unsigned)__shfl((int)pk[2*w  ][1], srcB);
      unsigned b0 = (unsigned)__shfl((int)pk[2*w+1][0], srcA);
      unsigned b1 = (unsigned)__shfl((int)pk[2*w+1][1], srcA);
      unsigned b2 = (unsigned)__shfl((int)pk[2*w+1][0], srcB);
      unsigned b3 = (unsigned)__shfl((int)pk[2*w+1][1], srcB);
      union { unsigned u[4]; bf16x8 v; } bfrag;
      bfrag.u[0] = hi ? b0 : a0;
      bfrag.u[1] = hi ? b1 : a1;
      bfrag.u[2] = hi ? b2 : a2;
      bfrag.u[3] = hi ? b3 : a3;
      #pragma unroll
      for (int mf=0; mf<4; mf++){
        bf16x8 af;
        #pragma unroll
        for (int j=0; j<8; j++) af[j] = Vs[w*32 + g*8 + j][mf*16 + qi];
        oacc[mf] = __builtin_amdgcn_mfma_f32_16x16x32_bf16(af, bfrag.v, oacc[mf], 0,0,0);
      }
    }
  }

  // ---- epilogue: O^T frags -> LDS -> coalesced bf16 store ----
  const float inv = 1.f / lrun;
  #pragma unroll
  for (int mf=0; mf<4; mf++)
    #pragma unroll
    for (int i=0; i<4; i++)
      Osh[wid*16 + qi][mf*16 + g*4 + i] = oacc[mf][i] * inv;
  __syncthreads();
  {
    const int orow = t >> 2;
    short tmp[16];
    #pragma unroll
    for (int e=0; e<16; e++) tmp[e] = f2bf(Osh[orow][c0 + e]);
    short* op = o + ((size_t)b*TT + q0 + orow)*DD + hh*64 + c0;
    *(bf16x8*)&op[0] = *(const bf16x8*)&tmp[0];
    *(bf16x8*)&op[8] = *(const bf16x8*)&tmp[8];
  }
}

extern "C" void kernel_launch(void* const* d_in, const int* in_sizes, int n_in,
                              void* d_out, int out_size, void* d_ws, size_t ws_size,
                              hipStream_t stream) {
  const int*   x      = (const int*)d_in[0];
  const float* tok    = (const float*)d_in[1];
  const float* pos    = (const float*)d_in[2];
  const float* attn_w = (const float*)d_in[3];
  const float* attn_b = (const float*)d_in[4];
  const float* proj_w = (const float*)d_in[5];
  const float* proj_b = (const float*)d_in[6];
  const float* ln1_g  = (const float*)d_in[7];
  const float* ln1_b  = (const float*)d_in[8];
  const float* ln2_g  = (const float*)d_in[9];
  const float* ln2_b  = (const float*)d_in[10];
  const float* ff1_w  = (const float*)d_in[11];
  const float* ff1_b  = (const float*)d_in[12];
  const float* ff2_w  = (const float*)d_in[13];
  const float* ff2_b  = (const float*)d_in[14];
  const float* lnf_g  = (const float*)d_in[15];
  const float* lnf_b  = (const float*)d_in[16];

  char* p = (char*)d_ws;
  float* h   = (float*)p; p += (size_t)ROWS*DD*4;
  short* hn  = (short*)p; p += (size_t)ROWS*DD*2;
  short* qkv = (short*)p; p += (size_t)ROWS*3*DD*2;
  short* ob  = (short*)p; p += (size_t)ROWS*DD*2;
  short* ffb = (short*)p; p += (size_t)ROWS*FFD*2;
  short* awT = (short*)p; p += (size_t)LL*3*DD*DD*2;
  short* pwT = (short*)p; p += (size_t)LL*DD*DD*2;
  short* f1T = (short*)p; p += (size_t)LL*FFD*DD*2;
  short* f2T = (short*)p; p += (size_t)LL*DD*FFD*2;
  short* lmT = (short*)p; p += (size_t)VV*DD*2;

  transpose_cast_kernel<<<dim3(48,16,8),256,0,stream>>>(attn_w, awT, DD, 3*DD);
  transpose_cast_kernel<<<dim3(16,16,8),256,0,stream>>>(proj_w, pwT, DD, DD);
  transpose_cast_kernel<<<dim3(64,16,8),256,0,stream>>>(ff1_w, f1T, DD, FFD);
  transpose_cast_kernel<<<dim3(16,64,8),256,0,stream>>>(ff2_w, f2T, FFD, DD);
  cast_kernel<<<128,256,0,stream>>>(tok, lmT, VV*DD);
  embed_kernel<<<ROWS,128,0,stream>>>(x, tok, pos, h);

  for (int l=0;l<LL;l++){
    ln_kernel<<<ROWS,256,0,stream>>>(h, ln1_g + l*DD, ln1_b + l*DD, hn);
    gemm_kernel<128,128,1><<<dim3(ROWS/128, (3*DD)/128),256,0,stream>>>(
        hn, awT + (size_t)l*3*DD*DD, attn_b + (size_t)l*3*DD, qkv, ROWS, 3*DD, DD);
    attn_kernel<<<dim3(TT/64, BB*HH),256,0,stream>>>(qkv, ob);
    gemm_kernel<128,128,3><<<dim3(ROWS/128, DD/128),256,0,stream>>>(
        ob, pwT + (size_t)l*DD*DD, proj_b + (size_t)l*DD, h, ROWS, DD, DD);
    ln_kernel<<<ROWS,256,0,stream>>>(h, ln2_g + l*DD, ln2_b + l*DD, hn);
    gemm_kernel<128,128,2><<<dim3(ROWS/128, FFD/128),256,0,stream>>>(
        hn, f1T + (size_t)l*FFD*DD, ff1_b + (size_t)l*FFD, ffb, ROWS, FFD, DD);
    gemm_kernel<128,128,3><<<dim3(ROWS/128, DD/128),256,0,stream>>>(
        ffb, f2T + (size_t)l*DD*FFD, ff2_b + (size_t)l*DD, h, ROWS, DD, FFD);
  }
  ln_kernel<<<ROWS,256,0,stream>>>(h, lnf_g, lnf_b, hn);
  gemm_kernel<64,64,0><<<dim3(ROWS/64, VV/64),256,0,stream>>>(
      hn, lmT, nullptr, d_out, ROWS, VV, DD);
}

// Round 3
// 2086.490 us; speedup vs baseline: 7.8701x; 1.0299x over previous
//
#include <hip/hip_runtime.h>

#define TT 2048
#define BB 4
#define DD 512
#define HH 8
#define LL 8
#define FFD 2048
#define VV 256
#define ROWS (BB*TT)

typedef short bf16x8 __attribute__((ext_vector_type(8)));
typedef float f32x4 __attribute__((ext_vector_type(4)));

#define GL2LDS(gp, lp) __builtin_amdgcn_global_load_lds( \
    (const __attribute__((address_space(1))) unsigned*)(gp), \
    (__attribute__((address_space(3))) unsigned*)(lp), 16, 0, 0)

__device__ __forceinline__ float bf2f(short s){
  union { unsigned u; float f; } x; x.u = ((unsigned)(unsigned short)s) << 16; return x.f;
}
__device__ __forceinline__ short f2bf(float f){
  union { float f; unsigned u; } x; x.f = f;
  unsigned r = (x.u + 0x7fffu + ((x.u >> 16) & 1u)) >> 16;
  return (short)(unsigned short)r;
}
__device__ __forceinline__ unsigned pack2(float lo, float hi){
  return (unsigned)(unsigned short)f2bf(lo) | ((unsigned)(unsigned short)f2bf(hi) << 16);
}

// ---------------- embedding ----------------
__global__ __launch_bounds__(128) void embed_kernel(const int* __restrict__ x,
    const float* __restrict__ tok, const float* __restrict__ pos, float* __restrict__ h){
  int row = blockIdx.x;
  int t = row & (TT-1);
  int id = x[row];
  const float4 a = *(const float4*)&tok[(size_t)id*DD + threadIdx.x*4];
  const float4 p = *(const float4*)&pos[(size_t)t*DD + threadIdx.x*4];
  float4 r; r.x=a.x+p.x; r.y=a.y+p.y; r.z=a.z+p.z; r.w=a.w+p.w;
  *(float4*)&h[(size_t)row*DD + threadIdx.x*4] = r;
}

// ---------------- LayerNorm (fp32 in, bf16 out) ----------------
__global__ __launch_bounds__(256) void ln_kernel(const float* __restrict__ xx,
    const float* __restrict__ g, const float* __restrict__ bb, short* __restrict__ out){
  __shared__ float sb[4];
  int row = blockIdx.x;
  int i = threadIdx.x*2;
  float2 xv = *(const float2*)&xx[(size_t)row*DD + i];
  int lane = threadIdx.x & 63, w = threadIdx.x >> 6;
  float s = xv.x + xv.y;
  #pragma unroll
  for (int off=32; off; off>>=1) s += __shfl_down(s, off);
  if (lane==0) sb[w] = s;
  __syncthreads();
  float m = (sb[0]+sb[1]+sb[2]+sb[3]) * (1.0f/DD);
  float dx = xv.x - m, dy = xv.y - m;
  float s2 = dx*dx + dy*dy;
  __syncthreads();
  #pragma unroll
  for (int off=32; off; off>>=1) s2 += __shfl_down(s2, off);
  if (lane==0) sb[w] = s2;
  __syncthreads();
  float var = (sb[0]+sb[1]+sb[2]+sb[3]) * (1.0f/DD);
  float rstd = rsqrtf(var + 1e-5f);
  out[(size_t)row*DD + i]   = f2bf(dx*rstd*g[i]   + bb[i]);
  out[(size_t)row*DD + i+1] = f2bf(dy*rstd*g[i+1] + bb[i+1]);
}

// ---------------- weight transpose+cast ----------------
__global__ __launch_bounds__(256) void transpose_cast_kernel(const float* __restrict__ src,
    short* __restrict__ dst, int R, int C){
  __shared__ float tile[32][33];
  size_t off = (size_t)blockIdx.z * R * C;
  src += off; dst += off;
  int c0 = blockIdx.x*32, r0 = blockIdx.y*32;
  int tx = threadIdx.x & 31, ty = threadIdx.x >> 5;
  #pragma unroll
  for (int i=0;i<4;i++) tile[ty + i*8][tx] = src[(size_t)(r0+ty+i*8)*C + c0 + tx];
  __syncthreads();
  #pragma unroll
  for (int i=0;i<4;i++) dst[(size_t)(c0+ty+i*8)*R + r0 + tx] = f2bf(tile[tx][ty+i*8]);
}

// ---------------- plain cast f32 -> bf16 ----------------
__global__ void cast_kernel(const float* __restrict__ in, short* __restrict__ out, int n){
  for (int i = blockIdx.x*blockDim.x + threadIdx.x; i < n; i += gridDim.x*blockDim.x)
    out[i] = f2bf(in[i]);
}

// ---------------- GEMM via global_load_lds (m97 structure), 128x128 tile, BK=64 ----------------
// EPI: 1 = +bias -> bf16; 2 = +bias,GELU -> bf16; 3 = +bias, residual += into f32
template<int EPI>
__global__ __launch_bounds__(256) void gemm_dma(const short* __restrict__ A,
    const short* __restrict__ BT, const float* __restrict__ bias, void* __restrict__ C,
    int M, int N, int K)
{
  __shared__ short As[128*64];
  __shared__ short Bs[128*64];
  const int row0 = blockIdx.x*128, col0 = blockIdx.y*128;
  const int t = threadIdx.x, lane = t & 63, w = t >> 6;
  const int wm = w >> 1, wn = w & 1;
  const int rr = lane & 15, g = lane >> 4;
  f32x4 acc[4][4];
  #pragma unroll
  for (int m=0;m<4;m++)
    #pragma unroll
    for (int n=0;n<4;n++) acc[m][n] = (f32x4){0.f,0.f,0.f,0.f};

  // DMA geometry: wave w instr i stages rows w*32+i*8 .. +7 (lane l -> row +l>>3, chunk l&7)
  const short* aP = A  + (size_t)(row0 + w*32 + (lane>>3))*K + (lane&7)*8;
  const short* bP = BT + (size_t)(col0 + w*32 + (lane>>3))*K + (lane&7)*8;
  short* aL = As + w*2048;
  short* bL = Bs + w*2048;

  for (int kt=0; kt<K; kt+=64){
    __syncthreads();
    #pragma unroll
    for (int i=0;i<4;i++){
      GL2LDS(aP + (size_t)i*8*K + kt, aL + i*512);
      GL2LDS(bP + (size_t)i*8*K + kt, bL + i*512);
    }
    __syncthreads();
    #pragma unroll
    for (int ks=0; ks<2; ks++){
      bf16x8 af[4], bfr[4];
      #pragma unroll
      for (int m=0;m<4;m++) af[m]  = *(const bf16x8*)&As[(wm*64 + m*16 + rr)*64 + ks*32 + g*8];
      #pragma unroll
      for (int n=0;n<4;n++) bfr[n] = *(const bf16x8*)&Bs[(wn*64 + n*16 + rr)*64 + ks*32 + g*8];
      #pragma unroll
      for (int m=0;m<4;m++)
        #pragma unroll
        for (int n=0;n<4;n++)
          acc[m][n] = __builtin_amdgcn_mfma_f32_16x16x32_bf16(af[m], bfr[n], acc[m][n], 0,0,0);
    }
  }
  #pragma unroll
  for (int m=0;m<4;m++){
    #pragma unroll
    for (int n=0;n<4;n++){
      int cg = col0 + wn*64 + n*16 + rr;
      float bv = bias[cg];
      #pragma unroll
      for (int i=0;i<4;i++){
        int rg = row0 + wm*64 + m*16 + g*4 + i;
        float v = acc[m][n][i] + bv;
        size_t idx = (size_t)rg*N + cg;
        if constexpr (EPI==1) ((short*)C)[idx] = f2bf(v);
        else if constexpr (EPI==2) { v = 0.5f*v*(1.0f + erff(v*0.70710678118f)); ((short*)C)[idx] = f2bf(v); }
        else { ((float*)C)[idx] += v; }
      }
    }
  }
}

// ---------------- small reg-staged GEMM (lm_head): C f32, no bias ----------------
template<int BM, int BN>
__global__ __launch_bounds__(256) void gemm_small(const short* __restrict__ A,
    const short* __restrict__ BT, float* __restrict__ C, int M, int N, int K)
{
  constexpr int FM = BM/32, FN = BN/32;
  __shared__ short As[BM][72];
  __shared__ short Bs[BN][72];
  const int row0 = blockIdx.x*BM, col0 = blockIdx.y*BN;
  const int t = threadIdx.x, lane = t & 63, w = t >> 6;
  const int wm = w >> 1, wn = w & 1;
  const int rr = lane & 15, kg = (lane >> 4)*8;
  f32x4 acc[FM][FN];
  #pragma unroll
  for (int m=0;m<FM;m++)
    #pragma unroll
    for (int n=0;n<FN;n++) acc[m][n] = (f32x4){0.f,0.f,0.f,0.f};

  for (int kt=0; kt<K; kt+=64){
    #pragma unroll
    for (int i=0;i<BM/32;i++){
      int cid = t + i*256; int r = cid >> 3; int c = (cid & 7)*8;
      *(bf16x8*)&As[r][c] = *(const bf16x8*)&A[(size_t)(row0+r)*K + kt + c];
    }
    #pragma unroll
    for (int i=0;i<BN/32;i++){
      int cid = t + i*256; int r = cid >> 3; int c = (cid & 7)*8;
      *(bf16x8*)&Bs[r][c] = *(const bf16x8*)&BT[(size_t)(col0+r)*K + kt + c];
    }
    __syncthreads();
    #pragma unroll
    for (int ks=0; ks<2; ks++){
      bf16x8 af[FM], bfr[FN];
      #pragma unroll
      for (int m=0;m<FM;m++) af[m] = *(const bf16x8*)&As[wm*FM*16 + m*16 + rr][ks*32 + kg];
      #pragma unroll
      for (int n=0;n<FN;n++) bfr[n] = *(const bf16x8*)&Bs[wn*FN*16 + n*16 + rr][ks*32 + kg];
      #pragma unroll
      for (int m=0;m<FM;m++)
        #pragma unroll
        for (int n=0;n<FN;n++)
          acc[m][n] = __builtin_amdgcn_mfma_f32_16x16x32_bf16(af[m], bfr[n], acc[m][n], 0,0,0);
    }
    __syncthreads();
  }
  #pragma unroll
  for (int m=0;m<FM;m++)
    #pragma unroll
    for (int n=0;n<FN;n++){
      int cg = col0 + wn*FN*16 + n*16 + rr;
      #pragma unroll
      for (int i=0;i<4;i++){
        int rg = row0 + wm*FM*16 + m*16 + (lane>>4)*4 + i;
        C[(size_t)rg*N + cg] = acc[m][n][i];
      }
    }
}

// ---------------- MFMA flash attention (DMA K staging + transposed V in LDS) ----------------
// grid (T/64, B*H), 256 threads = 4 waves; wave owns 16 q-rows.
// S^T = mfma(A=K, B=Q); O^T = mfma(A=V^T (b128 reads from Vt), B=P^T (shuffled)).
__global__ __launch_bounds__(256) void attn_kernel(const short* __restrict__ qkv, short* __restrict__ o){
  __shared__ __align__(16) char smem[17408];
  short* KsB = (short*)smem;            // [64][64] linear, chunk-swizzled (chunk ^= row&7)
  short* VtB = (short*)(smem + 8192);   // Vt[d][k] : [64][72]
  float* Osh = (float*)smem;            // [64][65] alias (epilogue only)

  const int b = blockIdx.y >> 3, hh = blockIdx.y & 7;
  const int qb = gridDim.x - 1 - blockIdx.x;   // heavy blocks first
  const int q0 = qb * 64;
  const int t = threadIdx.x, lane = t & 63, wid = t >> 6;
  const int g = lane >> 4, qi = lane & 15;
  const int qg = q0 + wid*16 + qi;
  const size_t base = (size_t)b*TT*3*DD + hh*64;

  bf16x8 qreg[2];
  {
    const short* qp = qkv + base + (size_t)qg*3*DD + g*8;
    qreg[0] = *(const bf16x8*)&qp[0];
    qreg[1] = *(const bf16x8*)&qp[32];
  }
  f32x4 oacc[4];
  #pragma unroll
  for (int mf=0; mf<4; mf++) oacc[mf] = (f32x4){0.f,0.f,0.f,0.f};
  float mrun = -1e30f, lrun = 0.f;

  // K DMA source: wave wid, instr i stages k-rows wid*16+i*8 .. +7; lane -> row l>>3, chunk (l&7)^(row&7)
  const short* ksrc0 = qkv + base + DD + (size_t)(wid*16 + (lane>>3))*3*DD
                       + (((lane&7) ^ ((lane>>3)&7))*8);
  short* kdst = KsB + wid*1024;
  // V: thread t loads V[vk][vd..vd+7], V[vk+1][vd..vd+7]; writes packed dwords into Vt
  const int vk = (t & 31)*2, vd = (t >> 5)*8;
  const short* vsrc0 = qkv + base + 2*DD + (size_t)vk*3*DD + vd;

  const int ntiles = qb + 1;
  for (int kb = 0; kb < ntiles; kb++){
    const size_t koff = (size_t)kb*64*3*DD;
    bf16x8 va = *(const bf16x8*)(vsrc0 + koff);
    bf16x8 vb = *(const bf16x8*)(vsrc0 + koff + 3*DD);
    __syncthreads();                       // prev tile's LDS reads done
    GL2LDS(ksrc0 + koff, kdst);
    GL2LDS(ksrc0 + koff + (size_t)8*3*DD, kdst + 512);
    #pragma unroll
    for (int e=0;e<8;e++)
      *(unsigned*)&VtB[(vd+e)*72 + vk] =
          (unsigned)(unsigned short)va[e] | ((unsigned)(unsigned short)vb[e] << 16);
    __syncthreads();                       // drains DMA (vmcnt) + LDS writes

    // ---- S^T = K * Q^T ----
    f32x4 sacc[4];
    #pragma unroll
    for (int f=0; f<4; f++) sacc[f] = (f32x4){0.f,0.f,0.f,0.f};
    #pragma unroll
    for (int ks=0; ks<2; ks++){
      #pragma unroll
      for (int f=0; f<4; f++){
        bf16x8 kf = *(const bf16x8*)&KsB[(f*16 + qi)*64 + (((ks*4 + g) ^ (qi&7))*8)];
        sacc[f] = __builtin_amdgcn_mfma_f32_16x16x32_bf16(kf, qreg[ks], sacc[f], 0,0,0);
      }
    }

    // ---- mask + online softmax (per-lane: one q, 16 keys) ----
    float p[4][4];
    float tm = -1e30f;
    #pragma unroll
    for (int f=0; f<4; f++)
      #pragma unroll
      for (int i=0; i<4; i++){
        int kgk = kb*64 + f*16 + g*4 + i;
        float s = sacc[f][i] * 0.125f;
        s = (kgk <= qg) ? s : -1e30f;
        p[f][i] = s;
        tm = fmaxf(tm, s);
      }
    tm = fmaxf(tm, __shfl_xor(tm, 16));
    tm = fmaxf(tm, __shfl_xor(tm, 32));
    float mnew = fmaxf(mrun, tm);
    float corr = __expf(mrun - mnew);
    float ts = 0.f;
    #pragma unroll
    for (int f=0; f<4; f++)
      #pragma unroll
      for (int i=0; i<4; i++){
        float e = __expf(p[f][i] - mnew);
        p[f][i] = e;
        ts += e;
      }
    ts += __shfl_xor(ts, 16);
    ts += __shfl_xor(ts, 32);
    lrun = lrun * corr + ts;
    mrun = mnew;
    #pragma unroll
    for (int mf=0; mf<4; mf++)
      #pragma unroll
      for (int i=0; i<4; i++) oacc[mf][i] *= corr;

    // ---- P^T shuffle + PV ----
    unsigned pk[4][2];
    #pragma unroll
    for (int f=0; f<4; f++){
      pk[f][0] = pack2(p[f][0], p[f][1]);
      pk[f][1] = pack2(p[f][2], p[f][3]);
    }
    const int srcA = ((g & 1) << 5) + qi;
    const int srcB = srcA + 16;
    const bool hi = (g >> 1) != 0;
    #pragma unroll
    for (int w2=0; w2<2; w2++){
      unsigned a0 = (unsigned)__shfl((int)pk[2*w2  ][0], srcA);
      unsigned a1 = (unsigned)__shfl((int)pk[2*w2  ][1], srcA);
      unsigned a2 = (unsigned)__shfl((int)pk[2*w2  ][0], srcB);
      unsigned a3 = (unsigned)__shfl((int)pk[2*w2  ][1], srcB);
      unsigned b0 = (unsigned)__shfl((int)pk[2*w2+1][0], srcA);
      unsigned b1 = (unsigned)__shfl((int)pk[2*w2+1][1], srcA);
      unsigned b2 = (unsigned)__shfl((int)pk[2*w2+1][0], srcB);
      unsigned b3 = (unsigned)__shfl((int)pk[2*w2+1][1], srcB);
      union { unsigned u[4]; bf16x8 v; } bfrag;
      bfrag.u[0] = hi ? b0 : a0;
      bfrag.u[1] = hi ? b1 : a1;
      bfrag.u[2] = hi ? b2 : a2;
      bfrag.u[3] = hi ? b3 : a3;
      #pragma unroll
      for (int mf=0; mf<4; mf++){
        bf16x8 af = *(const bf16x8*)&VtB[(mf*16 + qi)*72 + w2*32 + g*8];
        oacc[mf] = __builtin_amdgcn_mfma_f32_16x16x32_bf16(af, bfrag.v, oacc[mf], 0,0,0);
      }
    }
  }

  // ---- epilogue: O^T frags -> LDS (aliased) -> coalesced bf16 store ----
  __syncthreads();                         // all waves done with KsB/VtB
  const float inv = 1.f / lrun;
  #pragma unroll
  for (int mf=0; mf<4; mf++)
    #pragma unroll
    for (int i=0; i<4; i++)
      Osh[(wid*16 + qi)*65 + mf*16 + g*4 + i] = oacc[mf][i] * inv;
  __syncthreads();
  {
    const int orow = t >> 2, cc = (t & 3) * 16;
    short tmp[16];
    #pragma unroll
    for (int e=0; e<16; e++) tmp[e] = f2bf(Osh[orow*65 + cc + e]);
    short* op = o + ((size_t)b*TT + q0 + orow)*DD + hh*64 + cc;
    *(bf16x8*)&op[0] = *(const bf16x8*)&tmp[0];
    *(bf16x8*)&op[8] = *(const bf16x8*)&tmp[8];
  }
}

extern "C" void kernel_launch(void* const* d_in, const int* in_sizes, int n_in,
                              void* d_out, int out_size, void* d_ws, size_t ws_size,
                              hipStream_t stream) {
  const int*   x      = (const int*)d_in[0];
  const float* tok    = (const float*)d_in[1];
  const float* pos    = (const float*)d_in[2];
  const float* attn_w = (const float*)d_in[3];
  const float* attn_b = (const float*)d_in[4];
  const float* proj_w = (const float*)d_in[5];
  const float* proj_b = (const float*)d_in[6];
  const float* ln1_g  = (const float*)d_in[7];
  const float* ln1_b  = (const float*)d_in[8];
  const float* ln2_g  = (const float*)d_in[9];
  const float* ln2_b  = (const float*)d_in[10];
  const float* ff1_w  = (const float*)d_in[11];
  const float* ff1_b  = (const float*)d_in[12];
  const float* ff2_w  = (const float*)d_in[13];
  const float* ff2_b  = (const float*)d_in[14];
  const float* lnf_g  = (const float*)d_in[15];
  const float* lnf_b  = (const float*)d_in[16];

  char* p = (char*)d_ws;
  float* h   = (float*)p; p += (size_t)ROWS*DD*4;
  short* hn  = (short*)p; p += (size_t)ROWS*DD*2;
  short* qkv = (short*)p; p += (size_t)ROWS*3*DD*2;
  short* ob  = (short*)p; p += (size_t)ROWS*DD*2;
  short* ffb = (short*)p; p += (size_t)ROWS*FFD*2;
  short* awT = (short*)p; p += (size_t)LL*3*DD*DD*2;
  short* pwT = (short*)p; p += (size_t)LL*DD*DD*2;
  short* f1T = (short*)p; p += (size_t)LL*FFD*DD*2;
  short* f2T = (short*)p; p += (size_t)LL*DD*FFD*2;
  short* lmT = (short*)p; p += (size_t)VV*DD*2;

  transpose_cast_kernel<<<dim3(48,16,8),256,0,stream>>>(attn_w, awT, DD, 3*DD);
  transpose_cast_kernel<<<dim3(16,16,8),256,0,stream>>>(proj_w, pwT, DD, DD);
  transpose_cast_kernel<<<dim3(64,16,8),256,0,stream>>>(ff1_w, f1T, DD, FFD);
  transpose_cast_kernel<<<dim3(16,64,8),256,0,stream>>>(ff2_w, f2T, FFD, DD);
  cast_kernel<<<128,256,0,stream>>>(tok, lmT, VV*DD);
  embed_kernel<<<ROWS,128,0,stream>>>(x, tok, pos, h);

  for (int l=0;l<LL;l++){
    ln_kernel<<<ROWS,256,0,stream>>>(h, ln1_g + l*DD, ln1_b + l*DD, hn);
    gemm_dma<1><<<dim3(ROWS/128, (3*DD)/128),256,0,stream>>>(
        hn, awT + (size_t)l*3*DD*DD, attn_b + (size_t)l*3*DD, qkv, ROWS, 3*DD, DD);
    attn_kernel<<<dim3(TT/64, BB*HH),256,0,stream>>>(qkv, ob);
    gemm_dma<3><<<dim3(ROWS/128, DD/128),256,0,stream>>>(
        ob, pwT + (size_t)l*DD*DD, proj_b + (size_t)l*DD, h, ROWS, DD, DD);
    ln_kernel<<<ROWS,256,0,stream>>>(h, ln2_g + l*DD, ln2_b + l*DD, hn);
    gemm_dma<2><<<dim3(ROWS/128, FFD/128),256,0,stream>>>(
        hn, f1T + (size_t)l*FFD*DD, ff1_b + (size_t)l*FFD, ffb, ROWS, FFD, DD);
    gemm_dma<3><<<dim3(ROWS/128, DD/128),256,0,stream>>>(
        ffb, f2T + (size_t)l*DD*FFD, ff2_b + (size_t)l*DD, h, ROWS, DD, FFD);
  }
  ln_kernel<<<ROWS,256,0,stream>>>(h, lnf_g, lnf_b, hn);
  gemm_small<64,64><<<dim3(ROWS/64, VV/64),256,0,stream>>>(
      hn, lmT, (float*)d_out, ROWS, VV, DD);
}

// Round 4
// 2072.126 us; speedup vs baseline: 7.9246x; 1.0069x over previous
//
#include <hip/hip_runtime.h>

#define TT 2048
#define BB 4
#define DD 512
#define HH 8
#define LL 8
#define FFD 2048
#define VV 256
#define ROWS (BB*TT)

typedef short bf16x8 __attribute__((ext_vector_type(8)));
typedef float f32x4 __attribute__((ext_vector_type(4)));

#define GL2LDS(gp, lp) __builtin_amdgcn_global_load_lds( \
    (const __attribute__((address_space(1))) unsigned*)(gp), \
    (__attribute__((address_space(3))) unsigned*)(lp), 16, 0, 0)

__device__ __forceinline__ float bf2f(short s){
  union { unsigned u; float f; } x; x.u = ((unsigned)(unsigned short)s) << 16; return x.f;
}
__device__ __forceinline__ short f2bf(float f){
  union { float f; unsigned u; } x; x.f = f;
  unsigned r = (x.u + 0x7fffu + ((x.u >> 16) & 1u)) >> 16;
  return (short)(unsigned short)r;
}
__device__ __forceinline__ unsigned pack2(float lo, float hi){
  return (unsigned)(unsigned short)f2bf(lo) | ((unsigned)(unsigned short)f2bf(hi) << 16);
}

// ---------------- embedding ----------------
__global__ __launch_bounds__(128) void embed_kernel(const int* __restrict__ x,
    const float* __restrict__ tok, const float* __restrict__ pos, float* __restrict__ h){
  int row = blockIdx.x;
  int t = row & (TT-1);
  int id = x[row];
  const float4 a = *(const float4*)&tok[(size_t)id*DD + threadIdx.x*4];
  const float4 p = *(const float4*)&pos[(size_t)t*DD + threadIdx.x*4];
  float4 r; r.x=a.x+p.x; r.y=a.y+p.y; r.z=a.z+p.z; r.w=a.w+p.w;
  *(float4*)&h[(size_t)row*DD + threadIdx.x*4] = r;
}

// ---------------- LayerNorm (fp32 in, bf16 out) ----------------
__global__ __launch_bounds__(256) void ln_kernel(const float* __restrict__ xx,
    const float* __restrict__ g, const float* __restrict__ bb, short* __restrict__ out){
  __shared__ float sb[4];
  int row = blockIdx.x;
  int i = threadIdx.x*2;
  float2 xv = *(const float2*)&xx[(size_t)row*DD + i];
  int lane = threadIdx.x & 63, w = threadIdx.x >> 6;
  float s = xv.x + xv.y;
  #pragma unroll
  for (int off=32; off; off>>=1) s += __shfl_down(s, off);
  if (lane==0) sb[w] = s;
  __syncthreads();
  float m = (sb[0]+sb[1]+sb[2]+sb[3]) * (1.0f/DD);
  float dx = xv.x - m, dy = xv.y - m;
  float s2 = dx*dx + dy*dy;
  __syncthreads();
  #pragma unroll
  for (int off=32; off; off>>=1) s2 += __shfl_down(s2, off);
  if (lane==0) sb[w] = s2;
  __syncthreads();
  float var = (sb[0]+sb[1]+sb[2]+sb[3]) * (1.0f/DD);
  float rstd = rsqrtf(var + 1e-5f);
  out[(size_t)row*DD + i]   = f2bf(dx*rstd*g[i]   + bb[i]);
  out[(size_t)row*DD + i+1] = f2bf(dy*rstd*g[i+1] + bb[i+1]);
}

// ---------------- weight transpose+cast ----------------
__global__ __launch_bounds__(256) void transpose_cast_kernel(const float* __restrict__ src,
    short* __restrict__ dst, int R, int C){
  __shared__ float tile[32][33];
  size_t off = (size_t)blockIdx.z * R * C;
  src += off; dst += off;
  int c0 = blockIdx.x*32, r0 = blockIdx.y*32;
  int tx = threadIdx.x & 31, ty = threadIdx.x >> 5;
  #pragma unroll
  for (int i=0;i<4;i++) tile[ty + i*8][tx] = src[(size_t)(r0+ty+i*8)*C + c0 + tx];
  __syncthreads();
  #pragma unroll
  for (int i=0;i<4;i++) dst[(size_t)(c0+ty+i*8)*R + r0 + tx] = f2bf(tile[tx][ty+i*8]);
}

// ---------------- plain cast f32 -> bf16 ----------------
__global__ void cast_kernel(const float* __restrict__ in, short* __restrict__ out, int n){
  for (int i = blockIdx.x*blockDim.x + threadIdx.x; i < n; i += gridDim.x*blockDim.x)
    out[i] = f2bf(in[i]);
}

// ---------------- GEMM via global_load_lds (m97 structure), 128x128 tile, BK=64 ----------------
// EPI: 1 = +bias -> bf16; 2 = +bias,GELU -> bf16; 3 = +bias, residual += into f32
template<int EPI>
__global__ __launch_bounds__(256) void gemm_dma(const short* __restrict__ A,
    const short* __restrict__ BT, const float* __restrict__ bias, void* __restrict__ C,
    int M, int N, int K)
{
  __shared__ short As[128*64];
  __shared__ short Bs[128*64];
  const int row0 = blockIdx.x*128, col0 = blockIdx.y*128;
  const int t = threadIdx.x, lane = t & 63, w = t >> 6;
  const int wm = w >> 1, wn = w & 1;
  const int rr = lane & 15, g = lane >> 4;
  f32x4 acc[4][4];
  #pragma unroll
  for (int m=0;m<4;m++)
    #pragma unroll
    for (int n=0;n<4;n++) acc[m][n] = (f32x4){0.f,0.f,0.f,0.f};

  const short* aP = A  + (size_t)(row0 + w*32 + (lane>>3))*K + (lane&7)*8;
  const short* bP = BT + (size_t)(col0 + w*32 + (lane>>3))*K + (lane&7)*8;
  short* aL = As + w*2048;
  short* bL = Bs + w*2048;

  for (int kt=0; kt<K; kt+=64){
    __syncthreads();
    #pragma unroll
    for (int i=0;i<4;i++){
      GL2LDS(aP + (size_t)i*8*K + kt, aL + i*512);
      GL2LDS(bP + (size_t)i*8*K + kt, bL + i*512);
    }
    __syncthreads();
    #pragma unroll
    for (int ks=0; ks<2; ks++){
      bf16x8 af[4], bfr[4];
      #pragma unroll
      for (int m=0;m<4;m++) af[m]  = *(const bf16x8*)&As[(wm*64 + m*16 + rr)*64 + ks*32 + g*8];
      #pragma unroll
      for (int n=0;n<4;n++) bfr[n] = *(const bf16x8*)&Bs[(wn*64 + n*16 + rr)*64 + ks*32 + g*8];
      #pragma unroll
      for (int m=0;m<4;m++)
        #pragma unroll
        for (int n=0;n<4;n++)
          acc[m][n] = __builtin_amdgcn_mfma_f32_16x16x32_bf16(af[m], bfr[n], acc[m][n], 0,0,0);
    }
  }
  #pragma unroll
  for (int m=0;m<4;m++){
    #pragma unroll
    for (int n=0;n<4;n++){
      int cg = col0 + wn*64 + n*16 + rr;
      float bv = bias[cg];
      #pragma unroll
      for (int i=0;i<4;i++){
        int rg = row0 + wm*64 + m*16 + g*4 + i;
        float v = acc[m][n][i] + bv;
        size_t idx = (size_t)rg*N + cg;
        if constexpr (EPI==1) ((short*)C)[idx] = f2bf(v);
        else if constexpr (EPI==2) { v = 0.5f*v*(1.0f + erff(v*0.70710678118f)); ((short*)C)[idx] = f2bf(v); }
        else { ((float*)C)[idx] += v; }
      }
    }
  }
}

// ---------------- small reg-staged GEMM (lm_head): C f32, no bias ----------------
template<int BM, int BN>
__global__ __launch_bounds__(256) void gemm_small(const short* __restrict__ A,
    const short* __restrict__ BT, float* __restrict__ C, int M, int N, int K)
{
  constexpr int FM = BM/32, FN = BN/32;
  __shared__ short As[BM][72];
  __shared__ short Bs[BN][72];
  const int row0 = blockIdx.x*BM, col0 = blockIdx.y*BN;
  const int t = threadIdx.x, lane = t & 63, w = t >> 6;
  const int wm = w >> 1, wn = w & 1;
  const int rr = lane & 15, kg = (lane >> 4)*8;
  f32x4 acc[FM][FN];
  #pragma unroll
  for (int m=0;m<FM;m++)
    #pragma unroll
    for (int n=0;n<FN;n++) acc[m][n] = (f32x4){0.f,0.f,0.f,0.f};

  for (int kt=0; kt<K; kt+=64){
    #pragma unroll
    for (int i=0;i<BM/32;i++){
      int cid = t + i*256; int r = cid >> 3; int c = (cid & 7)*8;
      *(bf16x8*)&As[r][c] = *(const bf16x8*)&A[(size_t)(row0+r)*K + kt + c];
    }
    #pragma unroll
    for (int i=0;i<BN/32;i++){
      int cid = t + i*256; int r = cid >> 3; int c = (cid & 7)*8;
      *(bf16x8*)&Bs[r][c] = *(const bf16x8*)&BT[(size_t)(col0+r)*K + kt + c];
    }
    __syncthreads();
    #pragma unroll
    for (int ks=0; ks<2; ks++){
      bf16x8 af[FM], bfr[FN];
      #pragma unroll
      for (int m=0;m<FM;m++) af[m] = *(const bf16x8*)&As[wm*FM*16 + m*16 + rr][ks*32 + kg];
      #pragma unroll
      for (int n=0;n<FN;n++) bfr[n] = *(const bf16x8*)&Bs[wn*FN*16 + n*16 + rr][ks*32 + kg];
      #pragma unroll
      for (int m=0;m<FM;m++)
        #pragma unroll
        for (int n=0;n<FN;n++)
          acc[m][n] = __builtin_amdgcn_mfma_f32_16x16x32_bf16(af[m], bfr[n], acc[m][n], 0,0,0);
    }
    __syncthreads();
  }
  #pragma unroll
  for (int m=0;m<FM;m++)
    #pragma unroll
    for (int n=0;n<FN;n++){
      int cg = col0 + wn*FN*16 + n*16 + rr;
      #pragma unroll
      for (int i=0;i<4;i++){
        int rg = row0 + wm*FM*16 + m*16 + (lane>>4)*4 + i;
        C[(size_t)rg*N + cg] = acc[m][n][i];
      }
    }
}

// ---------------- MFMA flash attention, software-pipelined (1 barrier/tile, dbuf LDS) ----------------
// grid (T/64, B*H), 256 threads = 4 waves; wave owns 16 q-rows.
// Per tile: [write Vt(kb)->buf cur] BARRIER [issue K-DMA(kb+1)->buf nxt; load V(kb+1)] compute(kb)
__global__ __launch_bounds__(256) void attn_kernel(const short* __restrict__ qkv, short* __restrict__ o){
  __shared__ __align__(16) char smem[34816];
  short* KsB = (short*)smem;                 // 2 x [64][64] linear, chunk-swizzled (chunk ^= row&7)
  short* VtB = (short*)(smem + 16384);       // 2 x Vt[d][k] [64][72]
  float* Osh = (float*)smem;                 // [64][65] alias (epilogue only)

  const int b = blockIdx.y >> 3, hh = blockIdx.y & 7;
  const int qb = gridDim.x - 1 - blockIdx.x;   // heavy blocks first
  const int q0 = qb * 64;
  const int t = threadIdx.x, lane = t & 63, wid = t >> 6;
  const int g = lane >> 4, qi = lane & 15;
  const int qg = q0 + wid*16 + qi;
  const size_t base = (size_t)b*TT*3*DD + hh*64;

  bf16x8 qreg[2];
  {
    const short* qp = qkv + base + (size_t)qg*3*DD + g*8;
    qreg[0] = *(const bf16x8*)&qp[0];
    qreg[1] = *(const bf16x8*)&qp[32];
  }
  f32x4 oacc[4];
  #pragma unroll
  for (int mf=0; mf<4; mf++) oacc[mf] = (f32x4){0.f,0.f,0.f,0.f};
  float mrun = -1e30f, lrun = 0.f;

  // K DMA source: wave wid, instr i stages k-rows wid*16+i*8..+7; lane -> row l>>3, chunk (l&7)^(row&7)
  const short* ksrc0 = qkv + base + DD + (size_t)(wid*16 + (lane>>3))*3*DD
                       + (((lane&7) ^ ((lane>>3)&7))*8);
  // V: thread t loads V[vk][vd..vd+7], V[vk+1][vd..vd+7]; writes packed dwords into Vt
  const int vk = (t & 31)*2, vd = (t >> 5)*8;
  const short* vsrc0 = qkv + base + 2*DD + (size_t)vk*3*DD + vd;

  const int ntiles = qb + 1;
  // prologue: stage tile 0
  GL2LDS(ksrc0, KsB + wid*1024);
  GL2LDS(ksrc0 + (size_t)8*3*DD, KsB + wid*1024 + 512);
  bf16x8 va = *(const bf16x8*)(vsrc0);
  bf16x8 vb = *(const bf16x8*)(vsrc0 + 3*DD);

  for (int kb = 0; kb < ntiles; kb++){
    const int cur = kb & 1, nxt = cur ^ 1;
    const short* Kc = KsB + cur*4096;
    short* Vc = VtB + cur*4608;
    // write Vt(kb) into current buffer (reads of this buffer ended before previous barrier)
    #pragma unroll
    for (int e=0;e<8;e++)
      *(unsigned*)&Vc[(vd+e)*72 + vk] =
          (unsigned)(unsigned short)va[e] | ((unsigned)(unsigned short)vb[e] << 16);
    __syncthreads();   // drains K-DMA(kb) (vmcnt0) + Vt(kb) writes; all waves done reading bufs[nxt]
    if (kb+1 < ntiles){
      const size_t koff = (size_t)(kb+1)*64*3*DD;
      GL2LDS(ksrc0 + koff, KsB + nxt*4096 + wid*1024);
      GL2LDS(ksrc0 + koff + (size_t)8*3*DD, KsB + nxt*4096 + wid*1024 + 512);
      va = *(const bf16x8*)(vsrc0 + koff);
      vb = *(const bf16x8*)(vsrc0 + koff + 3*DD);
    }

    // ---- S^T = K * Q^T ----
    f32x4 sacc[4];
    #pragma unroll
    for (int f=0; f<4; f++) sacc[f] = (f32x4){0.f,0.f,0.f,0.f};
    __builtin_amdgcn_s_setprio(1);
    #pragma unroll
    for (int ks=0; ks<2; ks++){
      #pragma unroll
      for (int f=0; f<4; f++){
        bf16x8 kf = *(const bf16x8*)&Kc[(f*16 + qi)*64 + (((ks*4 + g) ^ (qi&7))*8)];
        sacc[f] = __builtin_amdgcn_mfma_f32_16x16x32_bf16(kf, qreg[ks], sacc[f], 0,0,0);
      }
    }
    __builtin_amdgcn_s_setprio(0);

    // ---- mask + online softmax (per-lane: one q, 16 keys) ----
    float p[4][4];
    float tm = -1e30f;
    #pragma unroll
    for (int f=0; f<4; f++)
      #pragma unroll
      for (int i=0; i<4; i++){
        int kgk = kb*64 + f*16 + g*4 + i;
        float s = sacc[f][i] * 0.125f;
        s = (kgk <= qg) ? s : -1e30f;
        p[f][i] = s;
        tm = fmaxf(tm, s);
      }
    tm = fmaxf(tm, __shfl_xor(tm, 16));
    tm = fmaxf(tm, __shfl_xor(tm, 32));
    float mnew = fmaxf(mrun, tm);
    float corr = __expf(mrun - mnew);
    float ts = 0.f;
    #pragma unroll
    for (int f=0; f<4; f++)
      #pragma unroll
      for (int i=0; i<4; i++){
        float e = __expf(p[f][i] - mnew);
        p[f][i] = e;
        ts += e;
      }
    ts += __shfl_xor(ts, 16);
    ts += __shfl_xor(ts, 32);
    lrun = lrun * corr + ts;
    mrun = mnew;
    #pragma unroll
    for (int mf=0; mf<4; mf++)
      #pragma unroll
      for (int i=0; i<4; i++) oacc[mf][i] *= corr;

    // ---- P^T shuffle + PV ----
    unsigned pk[4][2];
    #pragma unroll
    for (int f=0; f<4; f++){
      pk[f][0] = pack2(p[f][0], p[f][1]);
      pk[f][1] = pack2(p[f][2], p[f][3]);
    }
    const int srcA = ((g & 1) << 5) + qi;
    const int srcB = srcA + 16;
    const bool hi = (g >> 1) != 0;
    #pragma unroll
    for (int w2=0; w2<2; w2++){
      unsigned a0 = (unsigned)__shfl((int)pk[2*w2  ][0], srcA);
      unsigned a1 = (unsigned)__shfl((int)pk[2*w2  ][1], srcA);
      unsigned a2 = (unsigned)__shfl((int)pk[2*w2  ][0], srcB);
      unsigned a3 = (unsigned)__shfl((int)pk[2*w2  ][1], srcB);
      unsigned b0 = (unsigned)__shfl((int)pk[2*w2+1][0], srcA);
      unsigned b1 = (unsigned)__shfl((int)pk[2*w2+1][1], srcA);
      unsigned b2 = (unsigned)__shfl((int)pk[2*w2+1][0], srcB);
      unsigned b3 = (unsigned)__shfl((int)pk[2*w2+1][1], srcB);
      union { unsigned u[4]; bf16x8 v; } bfrag;
      bfrag.u[0] = hi ? b0 : a0;
      bfrag.u[1] = hi ? b1 : a1;
      bfrag.u[2] = hi ? b2 : a2;
      bfrag.u[3] = hi ? b3 : a3;
      __builtin_amdgcn_s_setprio(1);
      #pragma unroll
      for (int mf=0; mf<4; mf++){
        bf16x8 af = *(const bf16x8*)&Vc[(mf*16 + qi)*72 + w2*32 + g*8];
        oacc[mf] = __builtin_amdgcn_mfma_f32_16x16x32_bf16(af, bfrag.v, oacc[mf], 0,0,0);
      }
      __builtin_amdgcn_s_setprio(0);
    }
  }

  // ---- epilogue: O^T frags -> LDS (aliased) -> coalesced bf16 store ----
  __syncthreads();
  const float inv = 1.f / lrun;
  #pragma unroll
  for (int mf=0; mf<4; mf++)
    #pragma unroll
    for (int i=0; i<4; i++)
      Osh[(wid*16 + qi)*65 + mf*16 + g*4 + i] = oacc[mf][i] * inv;
  __syncthreads();
  {
    const int orow = t >> 2, cc = (t & 3) * 16;
    short tmp[16];
    #pragma unroll
    for (int e=0; e<16; e++) tmp[e] = f2bf(Osh[orow*65 + cc + e]);
    short* op = o + ((size_t)b*TT + q0 + orow)*DD + hh*64 + cc;
    *(bf16x8*)&op[0] = *(const bf16x8*)&tmp[0];
    *(bf16x8*)&op[8] = *(const bf16x8*)&tmp[8];
  }
}

extern "C" void kernel_launch(void* const* d_in, const int* in_sizes, int n_in,
                              void* d_out, int out_size, void* d_ws, size_t ws_size,
                              hipStream_t stream) {
  const int*   x      = (const int*)d_in[0];
  const float* tok    = (const float*)d_in[1];
  const float* pos    = (const float*)d_in[2];
  const float* attn_w = (const float*)d_in[3];
  const float* attn_b = (const float*)d_in[4];
  const float* proj_w = (const float*)d_in[5];
  const float* proj_b = (const float*)d_in[6];
  const float* ln1_g  = (const float*)d_in[7];
  const float* ln1_b  = (const float*)d_in[8];
  const float* ln2_g  = (const float*)d_in[9];
  const float* ln2_b  = (const float*)d_in[10];
  const float* ff1_w  = (const float*)d_in[11];
  const float* ff1_b  = (const float*)d_in[12];
  const float* ff2_w  = (const float*)d_in[13];
  const float* ff2_b  = (const float*)d_in[14];
  const float* lnf_g  = (const float*)d_in[15];
  const float* lnf_b  = (const float*)d_in[16];

  char* p = (char*)d_ws;
  float* h   = (float*)p; p += (size_t)ROWS*DD*4;
  short* hn  = (short*)p; p += (size_t)ROWS*DD*2;
  short* qkv = (short*)p; p += (size_t)ROWS*3*DD*2;
  short* ob  = (short*)p; p += (size_t)ROWS*DD*2;
  short* ffb = (short*)p; p += (size_t)ROWS*FFD*2;
  short* awT = (short*)p; p += (size_t)LL*3*DD*DD*2;
  short* pwT = (short*)p; p += (size_t)LL*DD*DD*2;
  short* f1T = (short*)p; p += (size_t)LL*FFD*DD*2;
  short* f2T = (short*)p; p += (size_t)LL*DD*FFD*2;
  short* lmT = (short*)p; p += (size_t)VV*DD*2;

  transpose_cast_kernel<<<dim3(48,16,8),256,0,stream>>>(attn_w, awT, DD, 3*DD);
  transpose_cast_kernel<<<dim3(16,16,8),256,0,stream>>>(proj_w, pwT, DD, DD);
  transpose_cast_kernel<<<dim3(64,16,8),256,0,stream>>>(ff1_w, f1T, DD, FFD);
  transpose_cast_kernel<<<dim3(16,64,8),256,0,stream>>>(ff2_w, f2T, FFD, DD);
  cast_kernel<<<128,256,0,stream>>>(tok, lmT, VV*DD);
  embed_kernel<<<ROWS,128,0,stream>>>(x, tok, pos, h);

  for (int l=0;l<LL;l++){
    ln_kernel<<<ROWS,256,0,stream>>>(h, ln1_g + l*DD, ln1_b + l*DD, hn);
    gemm_dma<1><<<dim3(ROWS/128, (3*DD)/128),256,0,stream>>>(
        hn, awT + (size_t)l*3*DD*DD, attn_b + (size_t)l*3*DD, qkv, ROWS, 3*DD, DD);
    attn_kernel<<<dim3(TT/64, BB*HH),256,0,stream>>>(qkv, ob);
    gemm_dma<3><<<dim3(ROWS/128, DD/128),256,0,stream>>>(
        ob, pwT + (size_t)l*DD*DD, proj_b + (size_t)l*DD, h, ROWS, DD, DD);
    ln_kernel<<<ROWS,256,0,stream>>>(h, ln2_g + l*DD, ln2_b + l*DD, hn);
    gemm_dma<2><<<dim3(ROWS/128, FFD/128),256,0,stream>>>(
        hn, f1T + (size_t)l*FFD*DD, ff1_b + (size_t)l*FFD, ffb, ROWS, FFD, DD);
    gemm_dma<3><<<dim3(ROWS/128, DD/128),256,0,stream>>>(
        ffb, f2T + (size_t)l*DD*FFD, ff2_b + (size_t)l*DD, h, ROWS, DD, FFD);
  }
  ln_kernel<<<ROWS,256,0,stream>>>(h, lnf_g, lnf_b, hn);
  gemm_small<64,64><<<dim3(ROWS/64, VV/64),256,0,stream>>>(
      hn, lmT, (float*)d_out, ROWS, VV, DD);
}

// Round 5
// 2049.937 us; speedup vs baseline: 8.0104x; 1.0108x over previous
//
#include <hip/hip_runtime.h>

#define TT 2048
#define BB 4
#define DD 512
#define HH 8
#define LL 8
#define FFD 2048
#define VV 256
#define ROWS (BB*TT)

typedef short bf16x8 __attribute__((ext_vector_type(8)));
typedef float f32x4 __attribute__((ext_vector_type(4)));

#define GL2LDS(gp, lp) __builtin_amdgcn_global_load_lds( \
    (const __attribute__((address_space(1))) unsigned*)(gp), \
    (__attribute__((address_space(3))) unsigned*)(lp), 16, 0, 0)

__device__ __forceinline__ float bf2f(short s){
  union { unsigned u; float f; } x; x.u = ((unsigned)(unsigned short)s) << 16; return x.f;
}
__device__ __forceinline__ short f2bf(float f){
  union { float f; unsigned u; } x; x.f = f;
  unsigned r = (x.u + 0x7fffu + ((x.u >> 16) & 1u)) >> 16;
  return (short)(unsigned short)r;
}
__device__ __forceinline__ unsigned pack2(float lo, float hi){
  return (unsigned)(unsigned short)f2bf(lo) | ((unsigned)(unsigned short)f2bf(hi) << 16);
}

// ---------------- embedding ----------------
__global__ __launch_bounds__(128) void embed_kernel(const int* __restrict__ x,
    const float* __restrict__ tok, const float* __restrict__ pos, float* __restrict__ h){
  int row = blockIdx.x;
  int t = row & (TT-1);
  int id = x[row];
  const float4 a = *(const float4*)&tok[(size_t)id*DD + threadIdx.x*4];
  const float4 p = *(const float4*)&pos[(size_t)t*DD + threadIdx.x*4];
  float4 r; r.x=a.x+p.x; r.y=a.y+p.y; r.z=a.z+p.z; r.w=a.w+p.w;
  *(float4*)&h[(size_t)row*DD + threadIdx.x*4] = r;
}

// ---------------- LayerNorm: one wave per row, no barriers ----------------
__global__ __launch_bounds__(256) void ln_kernel(const float* __restrict__ xx,
    const float* __restrict__ gw, const float* __restrict__ bw, short* __restrict__ out){
  const int lane = threadIdx.x & 63, w = threadIdx.x >> 6;
  const int row = blockIdx.x*4 + w;
  const float* xp = xx + (size_t)row*DD + lane*8;
  float4 a = *(const float4*)xp, c = *(const float4*)(xp+4);
  float xv[8] = {a.x,a.y,a.z,a.w,c.x,c.y,c.z,c.w};
  float s1 = 0.f, s2 = 0.f;
  #pragma unroll
  for (int e=0;e<8;e++){ s1 += xv[e]; s2 += xv[e]*xv[e]; }
  #pragma unroll
  for (int off=1; off<64; off<<=1){
    s1 += __shfl_xor(s1, off);
    s2 += __shfl_xor(s2, off);
  }
  const float m = s1 * (1.0f/DD);
  const float rstd = rsqrtf(s2*(1.0f/DD) - m*m + 1e-5f);
  const float4 g0 = *(const float4*)(gw + lane*8), g1 = *(const float4*)(gw + lane*8 + 4);
  const float4 b0 = *(const float4*)(bw + lane*8), b1 = *(const float4*)(bw + lane*8 + 4);
  float gg[8] = {g0.x,g0.y,g0.z,g0.w,g1.x,g1.y,g1.z,g1.w};
  float bb[8] = {b0.x,b0.y,b0.z,b0.w,b1.x,b1.y,b1.z,b1.w};
  short r[8];
  #pragma unroll
  for (int e=0;e<8;e++) r[e] = f2bf((xv[e]-m)*rstd*gg[e] + bb[e]);
  *(bf16x8*)&out[(size_t)row*DD + lane*8] = *(const bf16x8*)r;
}

// ---------------- weight transpose+cast ----------------
__global__ __launch_bounds__(256) void transpose_cast_kernel(const float* __restrict__ src,
    short* __restrict__ dst, int R, int C){
  __shared__ float tile[32][33];
  size_t off = (size_t)blockIdx.z * R * C;
  src += off; dst += off;
  int c0 = blockIdx.x*32, r0 = blockIdx.y*32;
  int tx = threadIdx.x & 31, ty = threadIdx.x >> 5;
  #pragma unroll
  for (int i=0;i<4;i++) tile[ty + i*8][tx] = src[(size_t)(r0+ty+i*8)*C + c0 + tx];
  __syncthreads();
  #pragma unroll
  for (int i=0;i<4;i++) dst[(size_t)(c0+ty+i*8)*R + r0 + tx] = f2bf(tile[tx][ty+i*8]);
}

// ---------------- plain cast f32 -> bf16 ----------------
__global__ void cast_kernel(const float* __restrict__ in, short* __restrict__ out, int n){
  for (int i = blockIdx.x*blockDim.x + threadIdx.x; i < n; i += gridDim.x*blockDim.x)
    out[i] = f2bf(in[i]);
}

// ---------------- GEMM via global_load_lds (m97 structure), 128x128 tile, BK=64 ----------------
// EPI: 1 = +bias -> bf16; 2 = +bias,GELU -> bf16; 3 = +bias, residual += into f32
template<int EPI>
__global__ __launch_bounds__(256) void gemm_dma(const short* __restrict__ A,
    const short* __restrict__ BT, const float* __restrict__ bias, void* __restrict__ C,
    int M, int N, int K)
{
  __shared__ short As[128*64];
  __shared__ short Bs[128*64];
  const int row0 = blockIdx.x*128, col0 = blockIdx.y*128;
  const int t = threadIdx.x, lane = t & 63, w = t >> 6;
  const int wm = w >> 1, wn = w & 1;
  const int rr = lane & 15, g = lane >> 4;
  f32x4 acc[4][4];
  #pragma unroll
  for (int m=0;m<4;m++)
    #pragma unroll
    for (int n=0;n<4;n++) acc[m][n] = (f32x4){0.f,0.f,0.f,0.f};

  const short* aP = A  + (size_t)(row0 + w*32 + (lane>>3))*K + (lane&7)*8;
  const short* bP = BT + (size_t)(col0 + w*32 + (lane>>3))*K + (lane&7)*8;
  short* aL = As + w*2048;
  short* bL = Bs + w*2048;

  for (int kt=0; kt<K; kt+=64){
    __syncthreads();
    #pragma unroll
    for (int i=0;i<4;i++){
      GL2LDS(aP + (size_t)i*8*K + kt, aL + i*512);
      GL2LDS(bP + (size_t)i*8*K + kt, bL + i*512);
    }
    __syncthreads();
    #pragma unroll
    for (int ks=0; ks<2; ks++){
      bf16x8 af[4], bfr[4];
      #pragma unroll
      for (int m=0;m<4;m++) af[m]  = *(const bf16x8*)&As[(wm*64 + m*16 + rr)*64 + ks*32 + g*8];
      #pragma unroll
      for (int n=0;n<4;n++) bfr[n] = *(const bf16x8*)&Bs[(wn*64 + n*16 + rr)*64 + ks*32 + g*8];
      #pragma unroll
      for (int m=0;m<4;m++)
        #pragma unroll
        for (int n=0;n<4;n++)
          acc[m][n] = __builtin_amdgcn_mfma_f32_16x16x32_bf16(af[m], bfr[n], acc[m][n], 0,0,0);
    }
  }
  #pragma unroll
  for (int m=0;m<4;m++){
    #pragma unroll
    for (int n=0;n<4;n++){
      int cg = col0 + wn*64 + n*16 + rr;
      float bv = bias[cg];
      #pragma unroll
      for (int i=0;i<4;i++){
        int rg = row0 + wm*64 + m*16 + g*4 + i;
        float v = acc[m][n][i] + bv;
        size_t idx = (size_t)rg*N + cg;
        if constexpr (EPI==1) ((short*)C)[idx] = f2bf(v);
        else if constexpr (EPI==2) { v = 0.5f*v*(1.0f + erff(v*0.70710678118f)); ((short*)C)[idx] = f2bf(v); }
        else { ((float*)C)[idx] += v; }
      }
    }
  }
}

// ---------------- small reg-staged GEMM (lm_head): C f32, no bias ----------------
template<int BM, int BN>
__global__ __launch_bounds__(256) void gemm_small(const short* __restrict__ A,
    const short* __restrict__ BT, float* __restrict__ C, int M, int N, int K)
{
  constexpr int FM = BM/32, FN = BN/32;
  __shared__ short As[BM][72];
  __shared__ short Bs[BN][72];
  const int row0 = blockIdx.x*BM, col0 = blockIdx.y*BN;
  const int t = threadIdx.x, lane = t & 63, w = t >> 6;
  const int wm = w >> 1, wn = w & 1;
  const int rr = lane & 15, kg = (lane >> 4)*8;
  f32x4 acc[FM][FN];
  #pragma unroll
  for (int m=0;m<FM;m++)
    #pragma unroll
    for (int n=0;n<FN;n++) acc[m][n] = (f32x4){0.f,0.f,0.f,0.f};

  for (int kt=0; kt<K; kt+=64){
    #pragma unroll
    for (int i=0;i<BM/32;i++){
      int cid = t + i*256; int r = cid >> 3; int c = (cid & 7)*8;
      *(bf16x8*)&As[r][c] = *(const bf16x8*)&A[(size_t)(row0+r)*K + kt + c];
    }
    #pragma unroll
    for (int i=0;i<BN/32;i++){
      int cid = t + i*256; int r = cid >> 3; int c = (cid & 7)*8;
      *(bf16x8*)&Bs[r][c] = *(const bf16x8*)&BT[(size_t)(col0+r)*K + kt + c];
    }
    __syncthreads();
    #pragma unroll
    for (int ks=0; ks<2; ks++){
      bf16x8 af[FM], bfr[FN];
      #pragma unroll
      for (int m=0;m<FM;m++) af[m] = *(const bf16x8*)&As[wm*FM*16 + m*16 + rr][ks*32 + kg];
      #pragma unroll
      for (int n=0;n<FN;n++) bfr[n] = *(const bf16x8*)&Bs[wn*FN*16 + n*16 + rr][ks*32 + kg];
      #pragma unroll
      for (int m=0;m<FM;m++)
        #pragma unroll
        for (int n=0;n<FN;n++)
          acc[m][n] = __builtin_amdgcn_mfma_f32_16x16x32_bf16(af[m], bfr[n], acc[m][n], 0,0,0);
    }
    __syncthreads();
  }
  #pragma unroll
  for (int m=0;m<FM;m++)
    #pragma unroll
    for (int n=0;n<FN;n++){
      int cg = col0 + wn*FN*16 + n*16 + rr;
      #pragma unroll
      for (int i=0;i<4;i++){
        int rg = row0 + wm*FM*16 + m*16 + (lane>>4)*4 + i;
        C[(size_t)rg*N + cg] = acc[m][n][i];
      }
    }
}

// ---------------- MFMA flash attention v3 ----------------
// grid (T/32, B*H), 128 threads = 2 waves; wave owns 16 q-rows (32/block).
// K double-buffered (DMA prefetch hidden under compute), Vt single, P via
// wave-private LDS (no cross-lane shuffles for the PV operand).
__global__ __launch_bounds__(128) void attn_kernel(const short* __restrict__ qkv, short* __restrict__ o){
  __shared__ __align__(16) char smem[30208];
  short* KsB = (short*)smem;                   // 2 x [64][64] linear, chunk^=(row&7)
  short* VtB = (short*)(smem + 16384);         // Vt[d][k] : [64][72]
  short* Pw  = (short*)(smem + 16384 + 9216);  // 2 waves x P[16 q][72 k]
  float* Osh = (float*)smem;                   // [32][65] alias (epilogue only)

  const int b = blockIdx.y >> 3, hh = blockIdx.y & 7;
  const int qb = gridDim.x - 1 - blockIdx.x;   // heavy blocks first
  const int q0 = qb * 32;
  const int t = threadIdx.x, lane = t & 63, wid = t >> 6;
  const int g = lane >> 4, qi = lane & 15;
  const int qg = q0 + wid*16 + qi;
  const size_t base = (size_t)b*TT*3*DD + hh*64;
  short* P = Pw + wid*16*72;

  // Q load, pre-scaled by 1/8 (exact exponent shift in bf16)
  bf16x8 qreg[2];
  {
    const short* qp = qkv + base + (size_t)qg*3*DD + g*8;
    qreg[0] = *(const bf16x8*)&qp[0];
    qreg[1] = *(const bf16x8*)&qp[32];
    #pragma unroll
    for (int j=0;j<8;j++){
      qreg[0][j] = f2bf(0.125f * bf2f(qreg[0][j]));
      qreg[1][j] = f2bf(0.125f * bf2f(qreg[1][j]));
    }
  }
  f32x4 oacc[4];
  #pragma unroll
  for (int mf=0; mf<4; mf++) oacc[mf] = (f32x4){0.f,0.f,0.f,0.f};
  float mrun = -1e30f, lrun = 0.f;

  // K DMA: wave wid covers k-rows wid*32+i*8+(lane>>3), source chunk (lane&7)^(lane>>3)
  const short* ksrc = qkv + base + DD + (size_t)(wid*32 + (lane>>3))*3*DD
                      + (((lane&7) ^ (lane>>3))*8);
  // V: thread t loads V[vk..vk+3][vd..vd+7]
  const int vk = (t & 15)*4, vd = (t >> 4)*8;
  const short* vsrc = qkv + base + 2*DD + (size_t)vk*3*DD + vd;

  const int nt = (q0 >> 6) + 1;
  // prologue: stage tile 0
  {
    short* kd = KsB + wid*2048;
    #pragma unroll
    for (int i=0;i<4;i++) GL2LDS(ksrc + (size_t)i*8*3*DD, kd + i*512);
  }
  bf16x8 vr0 = *(const bf16x8*)(vsrc);
  bf16x8 vr1 = *(const bf16x8*)(vsrc + 3*DD);
  bf16x8 vr2 = *(const bf16x8*)(vsrc + 6*DD);
  bf16x8 vr3 = *(const bf16x8*)(vsrc + 9*DD);

  for (int kb = 0; kb < nt; kb++){
    const int cur = kb & 1;
    __syncthreads();   // drains K-DMA(kb)+V(kb) regs (issued one compute-phase ago); Vt(kb-1) reads done
    #pragma unroll
    for (int e=0;e<8;e++){
      *(unsigned*)&VtB[(vd+e)*72 + vk] =
          (unsigned)(unsigned short)vr0[e] | ((unsigned)(unsigned short)vr1[e] << 16);
      *(unsigned*)&VtB[(vd+e)*72 + vk + 2] =
          (unsigned)(unsigned short)vr2[e] | ((unsigned)(unsigned short)vr3[e] << 16);
    }
    __syncthreads();   // Vt(kb) visible; nothing else outstanding (cheap drain)
    if (kb+1 < nt){
      const size_t koff = (size_t)(kb+1)*64*3*DD;
      short* kd = KsB + (cur^1)*4096 + wid*2048;
      #pragma unroll
      for (int i=0;i<4;i++) GL2LDS(ksrc + koff + (size_t)i*8*3*DD, kd + i*512);
      vr0 = *(const bf16x8*)(vsrc + koff);
      vr1 = *(const bf16x8*)(vsrc + koff + 3*DD);
      vr2 = *(const bf16x8*)(vsrc + koff + 6*DD);
      vr3 = *(const bf16x8*)(vsrc + koff + 9*DD);
      __builtin_amdgcn_sched_barrier(0);   // keep prefetch above the compute cluster
    }
    const short* Kc = KsB + cur*4096;

    // ---- S^T = K * Q^T (scores pre-scaled via Q) ----
    f32x4 sacc[4];
    #pragma unroll
    for (int f=0; f<4; f++) sacc[f] = (f32x4){0.f,0.f,0.f,0.f};
    __builtin_amdgcn_s_setprio(1);
    #pragma unroll
    for (int ks=0; ks<2; ks++){
      #pragma unroll
      for (int f=0; f<4; f++){
        bf16x8 kf = *(const bf16x8*)&Kc[(f*16 + qi)*64 + (((ks*4 + g) ^ (qi&7))*8)];
        sacc[f] = __builtin_amdgcn_mfma_f32_16x16x32_bf16(kf, qreg[ks], sacc[f], 0,0,0);
      }
    }
    __builtin_amdgcn_s_setprio(0);

    // ---- online softmax: mask only on the diagonal (last) tile ----
    float p[4][4];
    float tm = -1e30f;
    if (kb == nt-1){
      #pragma unroll
      for (int f=0; f<4; f++)
        #pragma unroll
        for (int i=0; i<4; i++){
          int kgk = kb*64 + f*16 + g*4 + i;
          float s = (kgk <= qg) ? sacc[f][i] : -1e30f;
          p[f][i] = s;
          tm = fmaxf(tm, s);
        }
    } else {
      #pragma unroll
      for (int f=0; f<4; f++)
        #pragma unroll
        for (int i=0; i<4; i++){
          p[f][i] = sacc[f][i];
          tm = fmaxf(tm, sacc[f][i]);
        }
    }
    tm = fmaxf(tm, __shfl_xor(tm, 16));
    tm = fmaxf(tm, __shfl_xor(tm, 32));
    if (!__all(tm <= mrun + 8.f)){       // defer-max (T13)
      float mnew = fmaxf(mrun, tm);
      float corr = __expf(mrun - mnew);
      lrun *= corr;
      #pragma unroll
      for (int mf=0; mf<4; mf++)
        #pragma unroll
        for (int i=0; i<4; i++) oacc[mf][i] *= corr;
      mrun = mnew;
    }
    float ts = 0.f;
    #pragma unroll
    for (int f=0; f<4; f++)
      #pragma unroll
      for (int i=0; i<4; i++){
        float e = __expf(p[f][i] - mrun);
        p[f][i] = e;
        ts += e;
      }
    ts += __shfl_xor(ts, 16);
    ts += __shfl_xor(ts, 32);
    lrun += ts;

    // ---- P -> wave-private LDS (bf16), then PV via b128 reads ----
    #pragma unroll
    for (int f=0; f<4; f++){
      *(unsigned*)&P[qi*72 + f*16 + g*4]     = pack2(p[f][0], p[f][1]);
      *(unsigned*)&P[qi*72 + f*16 + g*4 + 2] = pack2(p[f][2], p[f][3]);
    }
    __builtin_amdgcn_s_setprio(1);
    #pragma unroll
    for (int w2=0; w2<2; w2++){
      bf16x8 pb = *(const bf16x8*)&P[qi*72 + w2*32 + g*8];
      #pragma unroll
      for (int mf=0; mf<4; mf++){
        bf16x8 af = *(const bf16x8*)&VtB[(mf*16 + qi)*72 + w2*32 + g*8];
        oacc[mf] = __builtin_amdgcn_mfma_f32_16x16x32_bf16(af, pb, oacc[mf], 0,0,0);
      }
    }
    __builtin_amdgcn_s_setprio(0);
  }

  // ---- epilogue: O^T frags -> LDS (aliased) -> coalesced bf16 store ----
  __syncthreads();
  const float inv = 1.f / lrun;
  #pragma unroll
  for (int mf=0; mf<4; mf++)
    #pragma unroll
    for (int i=0; i<4; i++)
      Osh[(wid*16 + qi)*65 + mf*16 + g*4 + i] = oacc[mf][i] * inv;
  __syncthreads();
  {
    const int orow = t >> 2, cc = (t & 3) * 16;
    short tmp[16];
    #pragma unroll
    for (int e=0; e<16; e++) tmp[e] = f2bf(Osh[orow*65 + cc + e]);
    short* op = o + ((size_t)b*TT + q0 + orow)*DD + hh*64 + cc;
    *(bf16x8*)&op[0] = *(const bf16x8*)&tmp[0];
    *(bf16x8*)&op[8] = *(const bf16x8*)&tmp[8];
  }
}

extern "C" void kernel_launch(void* const* d_in, const int* in_sizes, int n_in,
                              void* d_out, int out_size, void* d_ws, size_t ws_size,
                              hipStream_t stream) {
  const int*   x      = (const int*)d_in[0];
  const float* tok    = (const float*)d_in[1];
  const float* pos    = (const float*)d_in[2];
  const float* attn_w = (const float*)d_in[3];
  const float* attn_b = (const float*)d_in[4];
  const float* proj_w = (const float*)d_in[5];
  const float* proj_b = (const float*)d_in[6];
  const float* ln1_g  = (const float*)d_in[7];
  const float* ln1_b  = (const float*)d_in[8];
  const float* ln2_g  = (const float*)d_in[9];
  const float* ln2_b  = (const float*)d_in[10];
  const float* ff1_w  = (const float*)d_in[11];
  const float* ff1_b  = (const float*)d_in[12];
  const float* ff2_w  = (const float*)d_in[13];
  const float* ff2_b  = (const float*)d_in[14];
  const float* lnf_g  = (const float*)d_in[15];
  const float* lnf_b  = (const float*)d_in[16];

  char* p = (char*)d_ws;
  float* h   = (float*)p; p += (size_t)ROWS*DD*4;
  short* hn  = (short*)p; p += (size_t)ROWS*DD*2;
  short* qkv = (short*)p; p += (size_t)ROWS*3*DD*2;
  short* ob  = (short*)p; p += (size_t)ROWS*DD*2;
  short* ffb = (short*)p; p += (size_t)ROWS*FFD*2;
  short* awT = (short*)p; p += (size_t)LL*3*DD*DD*2;
  short* pwT = (short*)p; p += (size_t)LL*DD*DD*2;
  short* f1T = (short*)p; p += (size_t)LL*FFD*DD*2;
  short* f2T = (short*)p; p += (size_t)LL*DD*FFD*2;
  short* lmT = (short*)p; p += (size_t)VV*DD*2;

  transpose_cast_kernel<<<dim3(48,16,8),256,0,stream>>>(attn_w, awT, DD, 3*DD);
  transpose_cast_kernel<<<dim3(16,16,8),256,0,stream>>>(proj_w, pwT, DD, DD);
  transpose_cast_kernel<<<dim3(64,16,8),256,0,stream>>>(ff1_w, f1T, DD, FFD);
  transpose_cast_kernel<<<dim3(16,64,8),256,0,stream>>>(ff2_w, f2T, FFD, DD);
  cast_kernel<<<128,256,0,stream>>>(tok, lmT, VV*DD);
  embed_kernel<<<ROWS,128,0,stream>>>(x, tok, pos, h);

  for (int l=0;l<LL;l++){
    ln_kernel<<<ROWS/4,256,0,stream>>>(h, ln1_g + l*DD, ln1_b + l*DD, hn);
    gemm_dma<1><<<dim3(ROWS/128, (3*DD)/128),256,0,stream>>>(
        hn, awT + (size_t)l*3*DD*DD, attn_b + (size_t)l*3*DD, qkv, ROWS, 3*DD, DD);
    attn_kernel<<<dim3(TT/32, BB*HH),128,0,stream>>>(qkv, ob);
    gemm_dma<3><<<dim3(ROWS/128, DD/128),256,0,stream>>>(
        ob, pwT + (size_t)l*DD*DD, proj_b + (size_t)l*DD, h, ROWS, DD, DD);
    ln_kernel<<<ROWS/4,256,0,stream>>>(h, ln2_g + l*DD, ln2_b + l*DD, hn);
    gemm_dma<2><<<dim3(ROWS/128, FFD/128),256,0,stream>>>(
        hn, f1T + (size_t)l*FFD*DD, ff1_b + (size_t)l*FFD, ffb, ROWS, FFD, DD);
    gemm_dma<3><<<dim3(ROWS/128, DD/128),256,0,stream>>>(
        ffb, f2T + (size_t)l*DD*FFD, ff2_b + (size_t)l*DD, h, ROWS, DD, FFD);
  }
  ln_kernel<<<ROWS/4,256,0,stream>>>(h, lnf_g, lnf_b, hn);
  gemm_small<64,64><<<dim3(ROWS/64, VV/64),256,0,stream>>>(
      hn, lmT, (float*)d_out, ROWS, VV, DD);
}

// Round 6
// 1934.561 us; speedup vs baseline: 8.4881x; 1.0596x over previous
//
#include <hip/hip_runtime.h>

#define TT 2048
#define BB 4
#define DD 512
#define HH 8
#define LL 8
#define FFD 2048
#define VV 256
#define ROWS (BB*TT)

typedef short bf16x4 __attribute__((ext_vector_type(4)));
typedef short bf16x8 __attribute__((ext_vector_type(8)));
typedef float f32x4 __attribute__((ext_vector_type(4)));

#define GL2LDS(gp, lp) __builtin_amdgcn_global_load_lds( \
    (const __attribute__((address_space(1))) unsigned*)(gp), \
    (__attribute__((address_space(3))) unsigned*)(lp), 16, 0, 0)

__device__ __forceinline__ float bf2f(short s){
  union { unsigned u; float f; } x; x.u = ((unsigned)(unsigned short)s) << 16; return x.f;
}
__device__ __forceinline__ short f2bf(float f){
  union { float f; unsigned u; } x; x.f = f;
  unsigned r = (x.u + 0x7fffu + ((x.u >> 16) & 1u)) >> 16;
  return (short)(unsigned short)r;
}
__device__ __forceinline__ float ex2(float x){       // D = 2^x
  float r; asm("v_exp_f32 %0, %1" : "=v"(r) : "v"(x)); return r;
}
__device__ __forceinline__ unsigned cvtpk(float lo, float hi){
  unsigned r; asm("v_cvt_pk_bf16_f32 %0, %1, %2" : "=v"(r) : "v"(lo), "v"(hi)); return r;
}

// ---------------- embedding ----------------
__global__ __launch_bounds__(128) void embed_kernel(const int* __restrict__ x,
    const float* __restrict__ tok, const float* __restrict__ pos, float* __restrict__ h){
  int row = blockIdx.x;
  int t = row & (TT-1);
  int id = x[row];
  const float4 a = *(const float4*)&tok[(size_t)id*DD + threadIdx.x*4];
  const float4 p = *(const float4*)&pos[(size_t)t*DD + threadIdx.x*4];
  float4 r; r.x=a.x+p.x; r.y=a.y+p.y; r.z=a.z+p.z; r.w=a.w+p.w;
  *(float4*)&h[(size_t)row*DD + threadIdx.x*4] = r;
}

// ---------------- LayerNorm: one wave per row ----------------
__global__ __launch_bounds__(256) void ln_kernel(const float* __restrict__ xx,
    const float* __restrict__ gw, const float* __restrict__ bw, short* __restrict__ out){
  const int lane = threadIdx.x & 63, w = threadIdx.x >> 6;
  const int row = blockIdx.x*4 + w;
  const float* xp = xx + (size_t)row*DD + lane*8;
  float4 a = *(const float4*)xp, c = *(const float4*)(xp+4);
  float xv[8] = {a.x,a.y,a.z,a.w,c.x,c.y,c.z,c.w};
  float s1 = 0.f, s2 = 0.f;
  #pragma unroll
  for (int e=0;e<8;e++){ s1 += xv[e]; s2 += xv[e]*xv[e]; }
  #pragma unroll
  for (int off=1; off<64; off<<=1){
    s1 += __shfl_xor(s1, off);
    s2 += __shfl_xor(s2, off);
  }
  const float m = s1 * (1.0f/DD);
  const float rstd = rsqrtf(s2*(1.0f/DD) - m*m + 1e-5f);
  const float4 g0 = *(const float4*)(gw + lane*8), g1 = *(const float4*)(gw + lane*8 + 4);
  const float4 b0 = *(const float4*)(bw + lane*8), b1 = *(const float4*)(bw + lane*8 + 4);
  float gg[8] = {g0.x,g0.y,g0.z,g0.w,g1.x,g1.y,g1.z,g1.w};
  float bb[8] = {b0.x,b0.y,b0.z,b0.w,b1.x,b1.y,b1.z,b1.w};
  short r[8];
  #pragma unroll
  for (int e=0;e<8;e++) r[e] = f2bf((xv[e]-m)*rstd*gg[e] + bb[e]);
  *(bf16x8*)&out[(size_t)row*DD + lane*8] = *(const bf16x8*)r;
}

// ---------------- weight transpose+cast ----------------
__global__ __launch_bounds__(256) void transpose_cast_kernel(const float* __restrict__ src,
    short* __restrict__ dst, int R, int C){
  __shared__ float tile[32][33];
  size_t off = (size_t)blockIdx.z * R * C;
  src += off; dst += off;
  int c0 = blockIdx.x*32, r0 = blockIdx.y*32;
  int tx = threadIdx.x & 31, ty = threadIdx.x >> 5;
  #pragma unroll
  for (int i=0;i<4;i++) tile[ty + i*8][tx] = src[(size_t)(r0+ty+i*8)*C + c0 + tx];
  __syncthreads();
  #pragma unroll
  for (int i=0;i<4;i++) dst[(size_t)(c0+ty+i*8)*R + r0 + tx] = f2bf(tile[tx][ty+i*8]);
}

// ---------------- plain cast f32 -> bf16 ----------------
__global__ void cast_kernel(const float* __restrict__ in, short* __restrict__ out, int n){
  for (int i = blockIdx.x*blockDim.x + threadIdx.x; i < n; i += gridDim.x*blockDim.x)
    out[i] = f2bf(in[i]);
}

// ---------------- GEMM via global_load_lds, 128x128 tile, BK=64, XCD swizzle ----------------
// EPI: 1 = +bias -> bf16; 2 = +bias,GELU -> bf16; 3 = +bias, residual += into f32
template<int EPI>
__global__ __launch_bounds__(256) void gemm_dma(const short* __restrict__ A,
    const short* __restrict__ BT, const float* __restrict__ bias, void* __restrict__ C,
    int M, int N, int K)
{
  __shared__ short As[128*64];
  __shared__ short Bs[128*64];
  const int gx = gridDim.x, nwg = gx*gridDim.y;
  int lin = blockIdx.y*gx + blockIdx.x;
  lin = (lin & 7)*(nwg >> 3) + (lin >> 3);          // bijective: nwg % 8 == 0
  const int row0 = (lin % gx)*128, col0 = (lin / gx)*128;
  const int t = threadIdx.x, lane = t & 63, w = t >> 6;
  const int wm = w >> 1, wn = w & 1;
  const int rr = lane & 15, g = lane >> 4;
  f32x4 acc[4][4];
  #pragma unroll
  for (int m=0;m<4;m++)
    #pragma unroll
    for (int n=0;n<4;n++) acc[m][n] = (f32x4){0.f,0.f,0.f,0.f};

  const short* aP = A  + (size_t)(row0 + w*32 + (lane>>3))*K + (lane&7)*8;
  const short* bP = BT + (size_t)(col0 + w*32 + (lane>>3))*K + (lane&7)*8;
  short* aL = As + w*2048;
  short* bL = Bs + w*2048;

  for (int kt=0; kt<K; kt+=64){
    __syncthreads();
    #pragma unroll
    for (int i=0;i<4;i++){
      GL2LDS(aP + (size_t)i*8*K + kt, aL + i*512);
      GL2LDS(bP + (size_t)i*8*K + kt, bL + i*512);
    }
    __syncthreads();
    #pragma unroll
    for (int ks=0; ks<2; ks++){
      bf16x8 af[4], bfr[4];
      #pragma unroll
      for (int m=0;m<4;m++) af[m]  = *(const bf16x8*)&As[(wm*64 + m*16 + rr)*64 + ks*32 + g*8];
      #pragma unroll
      for (int n=0;n<4;n++) bfr[n] = *(const bf16x8*)&Bs[(wn*64 + n*16 + rr)*64 + ks*32 + g*8];
      #pragma unroll
      for (int m=0;m<4;m++)
        #pragma unroll
        for (int n=0;n<4;n++)
          acc[m][n] = __builtin_amdgcn_mfma_f32_16x16x32_bf16(af[m], bfr[n], acc[m][n], 0,0,0);
    }
  }
  #pragma unroll
  for (int m=0;m<4;m++){
    #pragma unroll
    for (int n=0;n<4;n++){
      int cg = col0 + wn*64 + n*16 + rr;
      float bv = bias[cg];
      #pragma unroll
      for (int i=0;i<4;i++){
        int rg = row0 + wm*64 + m*16 + g*4 + i;
        float v = acc[m][n][i] + bv;
        size_t idx = (size_t)rg*N + cg;
        if constexpr (EPI==1) ((short*)C)[idx] = f2bf(v);
        else if constexpr (EPI==2) { v = 0.5f*v*(1.0f + erff(v*0.70710678118f)); ((short*)C)[idx] = f2bf(v); }
        else { ((float*)C)[idx] += v; }
      }
    }
  }
}

// ---------------- GEMM 128x64 tile (for N=512 GEMMs; 2x blocks), EPI=3 only ----------------
__global__ __launch_bounds__(256) void gemm_dma_n64(const short* __restrict__ A,
    const short* __restrict__ BT, const float* __restrict__ bias, float* __restrict__ C,
    int M, int N, int K)
{
  __shared__ short As[128*64];
  __shared__ short Bs[64*64];
  const int gx = gridDim.x, nwg = gx*gridDim.y;
  int lin = blockIdx.y*gx + blockIdx.x;
  lin = (lin & 7)*(nwg >> 3) + (lin >> 3);
  const int row0 = (lin % gx)*128, col0 = (lin / gx)*64;
  const int t = threadIdx.x, lane = t & 63, w = t >> 6;
  const int wm = w >> 1, wn = w & 1;
  const int rr = lane & 15, g = lane >> 4;
  f32x4 acc[4][2];
  #pragma unroll
  for (int m=0;m<4;m++)
    #pragma unroll
    for (int n=0;n<2;n++) acc[m][n] = (f32x4){0.f,0.f,0.f,0.f};

  const short* aP = A  + (size_t)(row0 + w*32 + (lane>>3))*K + (lane&7)*8;
  const short* bP = BT + (size_t)(col0 + w*16 + (lane>>3))*K + (lane&7)*8;
  short* aL = As + w*2048;
  short* bL = Bs + w*1024;

  for (int kt=0; kt<K; kt+=64){
    __syncthreads();
    #pragma unroll
    for (int i=0;i<4;i++) GL2LDS(aP + (size_t)i*8*K + kt, aL + i*512);
    #pragma unroll
    for (int i=0;i<2;i++) GL2LDS(bP + (size_t)i*8*K + kt, bL + i*512);
    __syncthreads();
    #pragma unroll
    for (int ks=0; ks<2; ks++){
      bf16x8 af[4], bfr[2];
      #pragma unroll
      for (int m=0;m<4;m++) af[m]  = *(const bf16x8*)&As[(wm*64 + m*16 + rr)*64 + ks*32 + g*8];
      #pragma unroll
      for (int n=0;n<2;n++) bfr[n] = *(const bf16x8*)&Bs[(wn*32 + n*16 + rr)*64 + ks*32 + g*8];
      #pragma unroll
      for (int m=0;m<4;m++)
        #pragma unroll
        for (int n=0;n<2;n++)
          acc[m][n] = __builtin_amdgcn_mfma_f32_16x16x32_bf16(af[m], bfr[n], acc[m][n], 0,0,0);
    }
  }
  #pragma unroll
  for (int m=0;m<4;m++){
    #pragma unroll
    for (int n=0;n<2;n++){
      int cg = col0 + wn*32 + n*16 + rr;
      float bv = bias[cg];
      #pragma unroll
      for (int i=0;i<4;i++){
        int rg = row0 + wm*64 + m*16 + g*4 + i;
        C[(size_t)rg*N + cg] += acc[m][n][i] + bv;
      }
    }
  }
}

// ---------------- small reg-staged GEMM (lm_head): C f32, no bias ----------------
template<int BM, int BN>
__global__ __launch_bounds__(256) void gemm_small(const short* __restrict__ A,
    const short* __restrict__ BT, float* __restrict__ C, int M, int N, int K)
{
  constexpr int FM = BM/32, FN = BN/32;
  __shared__ short As[BM][72];
  __shared__ short Bs[BN][72];
  const int row0 = blockIdx.x*BM, col0 = blockIdx.y*BN;
  const int t = threadIdx.x, lane = t & 63, w = t >> 6;
  const int wm = w >> 1, wn = w & 1;
  const int rr = lane & 15, kg = (lane >> 4)*8;
  f32x4 acc[FM][FN];
  #pragma unroll
  for (int m=0;m<FM;m++)
    #pragma unroll
    for (int n=0;n<FN;n++) acc[m][n] = (f32x4){0.f,0.f,0.f,0.f};

  for (int kt=0; kt<K; kt+=64){
    #pragma unroll
    for (int i=0;i<BM/32;i++){
      int cid = t + i*256; int r = cid >> 3; int c = (cid & 7)*8;
      *(bf16x8*)&As[r][c] = *(const bf16x8*)&A[(size_t)(row0+r)*K + kt + c];
    }
    #pragma unroll
    for (int i=0;i<BN/32;i++){
      int cid = t + i*256; int r = cid >> 3; int c = (cid & 7)*8;
      *(bf16x8*)&Bs[r][c] = *(const bf16x8*)&BT[(size_t)(col0+r)*K + kt + c];
    }
    __syncthreads();
    #pragma unroll
    for (int ks=0; ks<2; ks++){
      bf16x8 af[FM], bfr[FN];
      #pragma unroll
      for (int m=0;m<FM;m++) af[m] = *(const bf16x8*)&As[wm*FM*16 + m*16 + rr][ks*32 + kg];
      #pragma unroll
      for (int n=0;n<FN;n++) bfr[n] = *(const bf16x8*)&Bs[wn*FN*16 + n*16 + rr][ks*32 + kg];
      #pragma unroll
      for (int m=0;m<FM;m++)
        #pragma unroll
        for (int n=0;n<FN;n++)
          acc[m][n] = __builtin_amdgcn_mfma_f32_16x16x32_bf16(af[m], bfr[n], acc[m][n], 0,0,0);
    }
    __syncthreads();
  }
  #pragma unroll
  for (int m=0;m<FM;m++)
    #pragma unroll
    for (int n=0;n<FN;n++){
      int cg = col0 + wn*FN*16 + n*16 + rr;
      #pragma unroll
      for (int i=0;i<4;i++){
        int rg = row0 + wm*FM*16 + m*16 + (lane>>4)*4 + i;
        C[(size_t)rg*N + cg] = acc[m][n][i];
      }
    }
}

// ---------------- MFMA flash attention v4 ----------------
// grid (T/64, B*H), 256 threads = 4 waves; wave owns 16 q-rows.
// Raw-barrier pipeline: barrier1 drains vmcnt(0) (loads issued a full iter ago),
// barrier2 drains lgkm only (K-DMA for kb+1 stays in flight across it).
// PV B-frag is LANE-LOCAL via custom slot->k permutation (no shuffles, no P-LDS).
__global__ __launch_bounds__(256) void attn_kernel(const short* __restrict__ qkv, short* __restrict__ o){
  __shared__ __align__(16) char smem[25600];
  short* KsB = (short*)smem;             // 2 x [64][64], chunk-swizzled (chunk ^= row&7)
  short* VtB = (short*)(smem + 16384);   // Vt[d][k] : [64][72]
  float* Osh = (float*)smem;             // [64][65] alias (epilogue only)

  const int b = blockIdx.y >> 3, hh = blockIdx.y & 7;
  const int qb = gridDim.x - 1 - blockIdx.x;   // heavy blocks first
  const int q0 = qb * 64;
  const int t = threadIdx.x, lane = t & 63, wid = t >> 6;
  const int g = lane >> 4, qi = lane & 15;
  const int qg = q0 + wid*16 + qi;
  const size_t base = (size_t)b*TT*3*DD + hh*64;

  // Q pre-scaled by 0.125*log2(e): scores come out in exp2 domain
  bf16x8 qreg[2];
  {
    const short* qp = qkv + base + (size_t)qg*3*DD + g*8;
    qreg[0] = *(const bf16x8*)&qp[0];
    qreg[1] = *(const bf16x8*)&qp[32];
    const float qs = 0.125f * 1.44269504f;
    #pragma unroll
    for (int j=0;j<8;j++){
      qreg[0][j] = f2bf(qs * bf2f(qreg[0][j]));
      qreg[1][j] = f2bf(qs * bf2f(qreg[1][j]));
    }
  }
  f32x4 oacc[4];
  #pragma unroll
  for (int mf=0; mf<4; mf++) oacc[mf] = (f32x4){0.f,0.f,0.f,0.f};
  float mrun = -1e30f, lrun = 0.f;

  // K DMA: wave wid stages k-rows wid*16+i*8+(lane>>3); src chunk (lane&7)^(lane>>3)
  const short* ksrc = qkv + base + DD + (size_t)(wid*16 + (lane>>3))*3*DD
                      + (((lane&7) ^ (lane>>3))*8);
  // V: thread loads V[vk][vd..vd+7], V[vk+1][vd..vd+7]
  const int vk = (t & 31)*2, vd = (t >> 5)*8;
  const short* vsrc = qkv + base + 2*DD + (size_t)vk*3*DD + vd;

  const int nt = qb + 1;
  // prologue: stage tile 0
  GL2LDS(ksrc, KsB + wid*1024);
  GL2LDS(ksrc + (size_t)8*3*DD, KsB + wid*1024 + 512);
  bf16x8 va = *(const bf16x8*)vsrc;
  bf16x8 vb = *(const bf16x8*)(vsrc + 3*DD);

  for (int kb = 0; kb < nt; kb++){
    const int cur = kb & 1;
    // ---- barrier1: all PV(kb-1) reads done; K-DMA(kb)+V(kb) (issued last iter) drained
    asm volatile("s_waitcnt vmcnt(0) lgkmcnt(0)\n\ts_barrier" ::: "memory");
    // prefetch tile kb+1 (flies across barrier2, drains at next barrier1)
    bf16x8 nva, nvb;
    if (kb+1 < nt){
      const size_t koff = (size_t)(kb+1)*64*3*DD;
      short* kd = KsB + (cur^1)*4096 + wid*1024;
      GL2LDS(ksrc + koff, kd);
      GL2LDS(ksrc + koff + (size_t)8*3*DD, kd + 512);
      nva = *(const bf16x8*)(vsrc + koff);
      nvb = *(const bf16x8*)(vsrc + koff + 3*DD);
    }
    // write Vt(kb)
    #pragma unroll
    for (int e=0;e<8;e++)
      *(unsigned*)&VtB[(vd+e)*72 + vk] =
          (unsigned)(unsigned short)va[e] | ((unsigned)(unsigned short)vb[e] << 16);

    // ---- S^T = K * Q^T ----
    const short* Kc = KsB + cur*4096;
    f32x4 sacc[4];
    #pragma unroll
    for (int f=0; f<4; f++) sacc[f] = (f32x4){0.f,0.f,0.f,0.f};
    __builtin_amdgcn_s_setprio(1);
    #pragma unroll
    for (int ks=0; ks<2; ks++){
      #pragma unroll
      for (int f=0; f<4; f++){
        bf16x8 kf = *(const bf16x8*)&Kc[(f*16 + qi)*64 + (((ks*4 + g) ^ (qi&7))*8)];
        sacc[f] = __builtin_amdgcn_mfma_f32_16x16x32_bf16(kf, qreg[ks], sacc[f], 0,0,0);
      }
    }
    __builtin_amdgcn_s_setprio(0);

    // ---- online softmax, exp2 domain; mask only diagonal tile ----
    float p[4][4];
    if (kb == nt-1){
      #pragma unroll
      for (int f=0; f<4; f++)
        #pragma unroll
        for (int i=0; i<4; i++){
          int kgk = kb*64 + f*16 + g*4 + i;
          p[f][i] = (kgk <= qg) ? sacc[f][i] : -1e30f;
        }
    } else {
      #pragma unroll
      for (int f=0; f<4; f++)
        #pragma unroll
        for (int i=0; i<4; i++) p[f][i] = sacc[f][i];
    }
    float m0 = fmaxf(fmaxf(p[0][0],p[0][1]), fmaxf(p[0][2],p[0][3]));
    float m1 = fmaxf(fmaxf(p[1][0],p[1][1]), fmaxf(p[1][2],p[1][3]));
    float m2 = fmaxf(fmaxf(p[2][0],p[2][1]), fmaxf(p[2][2],p[2][3]));
    float m3 = fmaxf(fmaxf(p[3][0],p[3][1]), fmaxf(p[3][2],p[3][3]));
    float tm = fmaxf(fmaxf(m0,m1), fmaxf(m2,m3));
    tm = fmaxf(tm, __shfl_xor(tm, 16));
    tm = fmaxf(tm, __shfl_xor(tm, 32));
    if (!__all(tm <= mrun + 8.f)){               // defer-max (log2 units)
      float mnew = fmaxf(mrun, tm);
      float corr = ex2(mrun - mnew);
      lrun *= corr;
      #pragma unroll
      for (int mf=0; mf<4; mf++)
        #pragma unroll
        for (int i=0; i<4; i++) oacc[mf][i] *= corr;
      mrun = mnew;
    }
    float ts = 0.f;
    #pragma unroll
    for (int f=0; f<4; f++)
      #pragma unroll
      for (int i=0; i<4; i++){
        float e = ex2(p[f][i] - mrun);
        p[f][i] = e;
        ts += e;
      }
    ts += __shfl_xor(ts, 16);
    ts += __shfl_xor(ts, 32);
    lrun += ts;

    // ---- barrier2: Vt(kb) visible; LDS-only drain (DMA stays in flight) ----
    asm volatile("s_waitcnt lgkmcnt(0)\n\ts_barrier" ::: "memory");

    // ---- PV: B-frag lane-local (slot j <-> k = 32w2+16(j>>2)+4g+(j&3)) ----
    __builtin_amdgcn_s_setprio(1);
    #pragma unroll
    for (int w2=0; w2<2; w2++){
      union { unsigned u[4]; bf16x8 v; } bfr;
      bfr.u[0] = cvtpk(p[2*w2  ][0], p[2*w2  ][1]);
      bfr.u[1] = cvtpk(p[2*w2  ][2], p[2*w2  ][3]);
      bfr.u[2] = cvtpk(p[2*w2+1][0], p[2*w2+1][1]);
      bfr.u[3] = cvtpk(p[2*w2+1][2], p[2*w2+1][3]);
      #pragma unroll
      for (int mf=0; mf<4; mf++){
        const short* vp = &VtB[(mf*16 + qi)*72 + w2*32 + g*4];
        union { bf16x4 h[2]; bf16x8 v; } af;
        af.h[0] = *(const bf16x4*)vp;          // k = +0..3
        af.h[1] = *(const bf16x4*)(vp + 16);   // k = +16..19
        oacc[mf] = __builtin_amdgcn_mfma_f32_16x16x32_bf16(af.v, bfr.v, oacc[mf], 0,0,0);
      }
    }
    __builtin_amdgcn_s_setprio(0);
    if (kb+1 < nt){ va = nva; vb = nvb; }
  }

  // ---- epilogue: O^T frags -> LDS (aliased) -> coalesced bf16 store ----
  __syncthreads();
  const float inv = 1.f / lrun;
  #pragma unroll
  for (int mf=0; mf<4; mf++)
    #pragma unroll
    for (int i=0; i<4; i++)
      Osh[(wid*16 + qi)*65 + mf*16 + g*4 + i] = oacc[mf][i] * inv;
  __syncthreads();
  {
    const int orow = t >> 2, cc = (t & 3) * 16;
    short tmp[16];
    #pragma unroll
    for (int e=0; e<16; e++) tmp[e] = f2bf(Osh[orow*65 + cc + e]);
    short* op = o + ((size_t)b*TT + q0 + orow)*DD + hh*64 + cc;
    *(bf16x8*)&op[0] = *(const bf16x8*)&tmp[0];
    *(bf16x8*)&op[8] = *(const bf16x8*)&tmp[8];
  }
}

extern "C" void kernel_launch(void* const* d_in, const int* in_sizes, int n_in,
                              void* d_out, int out_size, void* d_ws, size_t ws_size,
                              hipStream_t stream) {
  const int*   x      = (const int*)d_in[0];
  const float* tok    = (const float*)d_in[1];
  const float* pos    = (const float*)d_in[2];
  const float* attn_w = (const float*)d_in[3];
  const float* attn_b = (const float*)d_in[4];
  const float* proj_w = (const float*)d_in[5];
  const float* proj_b = (const float*)d_in[6];
  const float* ln1_g  = (const float*)d_in[7];
  const float* ln1_b  = (const float*)d_in[8];
  const float* ln2_g  = (const float*)d_in[9];
  const float* ln2_b  = (const float*)d_in[10];
  const float* ff1_w  = (const float*)d_in[11];
  const float* ff1_b  = (const float*)d_in[12];
  const float* ff2_w  = (const float*)d_in[13];
  const float* ff2_b  = (const float*)d_in[14];
  const float* lnf_g  = (const float*)d_in[15];
  const float* lnf_b  = (const float*)d_in[16];

  char* p = (char*)d_ws;
  float* h   = (float*)p; p += (size_t)ROWS*DD*4;
  short* hn  = (short*)p; p += (size_t)ROWS*DD*2;
  short* qkv = (short*)p; p += (size_t)ROWS*3*DD*2;
  short* ob  = (short*)p; p += (size_t)ROWS*DD*2;
  short* ffb = (short*)p; p += (size_t)ROWS*FFD*2;
  short* awT = (short*)p; p += (size_t)LL*3*DD*DD*2;
  short* pwT = (short*)p; p += (size_t)LL*DD*DD*2;
  short* f1T = (short*)p; p += (size_t)LL*FFD*DD*2;
  short* f2T = (short*)p; p += (size_t)LL*DD*FFD*2;
  short* lmT = (short*)p; p += (size_t)VV*DD*2;

  transpose_cast_kernel<<<dim3(48,16,8),256,0,stream>>>(attn_w, awT, DD, 3*DD);
  transpose_cast_kernel<<<dim3(16,16,8),256,0,stream>>>(proj_w, pwT, DD, DD);
  transpose_cast_kernel<<<dim3(64,16,8),256,0,stream>>>(ff1_w, f1T, DD, FFD);
  transpose_cast_kernel<<<dim3(16,64,8),256,0,stream>>>(ff2_w, f2T, FFD, DD);
  cast_kernel<<<128,256,0,stream>>>(tok, lmT, VV*DD);
  embed_kernel<<<ROWS,128,0,stream>>>(x, tok, pos, h);

  for (int l=0;l<LL;l++){
    ln_kernel<<<ROWS/4,256,0,stream>>>(h, ln1_g + l*DD, ln1_b + l*DD, hn);
    gemm_dma<1><<<dim3(ROWS/128, (3*DD)/128),256,0,stream>>>(
        hn, awT + (size_t)l*3*DD*DD, attn_b + (size_t)l*3*DD, qkv, ROWS, 3*DD, DD);
    attn_kernel<<<dim3(TT/64, BB*HH),256,0,stream>>>(qkv, ob);
    gemm_dma_n64<<<dim3(ROWS/128, DD/64),256,0,stream>>>(
        ob, pwT + (size_t)l*DD*DD, proj_b + (size_t)l*DD, h, ROWS, DD, DD);
    ln_kernel<<<ROWS/4,256,0,stream>>>(h, ln2_g + l*DD, ln2_b + l*DD, hn);
    gemm_dma<2><<<dim3(ROWS/128, FFD/128),256,0,stream>>>(
        hn, f1T + (size_t)l*FFD*DD, ff1_b + (size_t)l*FFD, ffb, ROWS, FFD, DD);
    gemm_dma_n64<<<dim3(ROWS/128, DD/64),256,0,stream>>>(
        ffb, f2T + (size_t)l*DD*FFD, ff2_b + (size_t)l*DD, h, ROWS, DD, FFD);
  }
  ln_kernel<<<ROWS/4,256,0,stream>>>(h, lnf_g, lnf_b, hn);
  gemm_small<64,64><<<dim3(ROWS/64, VV/64),256,0,stream>>>(
      hn, lmT, (float*)d_out, ROWS, VV, DD);
}

// Round 8
// 1643.157 us; speedup vs baseline: 9.9935x; 1.1773x over previous
//
#include <hip/hip_runtime.h>

#define TT 2048
#define BB 4
#define DD 512
#define HH 8
#define LL 8
#define FFD 2048
#define VV 256
#define ROWS (BB*TT)

typedef short bf16x4 __attribute__((ext_vector_type(4)));
typedef short bf16x8 __attribute__((ext_vector_type(8)));
typedef float f32x4 __attribute__((ext_vector_type(4)));

#define GL2LDS(gp, lp) __builtin_amdgcn_global_load_lds( \
    (const __attribute__((address_space(1))) unsigned*)(gp), \
    (__attribute__((address_space(3))) unsigned*)(lp), 16, 0, 0)

__device__ __forceinline__ float bf2f(short s){
  union { unsigned u; float f; } x; x.u = ((unsigned)(unsigned short)s) << 16; return x.f;
}
__device__ __forceinline__ short f2bf(float f){
  union { float f; unsigned u; } x; x.f = f;
  unsigned r = (x.u + 0x7fffu + ((x.u >> 16) & 1u)) >> 16;
  return (short)(unsigned short)r;
}
__device__ __forceinline__ float ex2(float x){
  float r; asm("v_exp_f32 %0, %1" : "=v"(r) : "v"(x)); return r;
}
__device__ __forceinline__ unsigned cvtpk(float lo, float hi){
  unsigned r; asm("v_cvt_pk_bf16_f32 %0, %1, %2" : "=v"(r) : "v"(lo), "v"(hi)); return r;
}
// proven cross-32 combines (R6): shfl_xor over full 64-wide wave
__device__ __forceinline__ float xmax32(float x){ return fmaxf(x, __shfl_xor(x, 32)); }
__device__ __forceinline__ float xadd32(float x){ return x + __shfl_xor(x, 32); }

// ---------------- embedding ----------------
__global__ __launch_bounds__(128) void embed_kernel(const int* __restrict__ x,
    const float* __restrict__ tok, const float* __restrict__ pos, float* __restrict__ h){
  int row = blockIdx.x;
  int t = row & (TT-1);
  int id = x[row];
  const float4 a = *(const float4*)&tok[(size_t)id*DD + threadIdx.x*4];
  const float4 p = *(const float4*)&pos[(size_t)t*DD + threadIdx.x*4];
  float4 r; r.x=a.x+p.x; r.y=a.y+p.y; r.z=a.z+p.z; r.w=a.w+p.w;
  *(float4*)&h[(size_t)row*DD + threadIdx.x*4] = r;
}

// ---------------- LayerNorm: one wave per row ----------------
__global__ __launch_bounds__(256) void ln_kernel(const float* __restrict__ xx,
    const float* __restrict__ gw, const float* __restrict__ bw, short* __restrict__ out){
  const int lane = threadIdx.x & 63, w = threadIdx.x >> 6;
  const int row = blockIdx.x*4 + w;
  const float* xp = xx + (size_t)row*DD + lane*8;
  float4 a = *(const float4*)xp, c = *(const float4*)(xp+4);
  float xv[8] = {a.x,a.y,a.z,a.w,c.x,c.y,c.z,c.w};
  float s1 = 0.f, s2 = 0.f;
  #pragma unroll
  for (int e=0;e<8;e++){ s1 += xv[e]; s2 += xv[e]*xv[e]; }
  #pragma unroll
  for (int off=1; off<64; off<<=1){
    s1 += __shfl_xor(s1, off);
    s2 += __shfl_xor(s2, off);
  }
  const float m = s1 * (1.0f/DD);
  const float rstd = rsqrtf(s2*(1.0f/DD) - m*m + 1e-5f);
  const float4 g0 = *(const float4*)(gw + lane*8), g1 = *(const float4*)(gw + lane*8 + 4);
  const float4 b0 = *(const float4*)(bw + lane*8), b1 = *(const float4*)(bw + lane*8 + 4);
  float gg[8] = {g0.x,g0.y,g0.z,g0.w,g1.x,g1.y,g1.z,g1.w};
  float bb[8] = {b0.x,b0.y,b0.z,b0.w,b1.x,b1.y,b1.z,b1.w};
  short r[8];
  #pragma unroll
  for (int e=0;e<8;e++) r[e] = f2bf((xv[e]-m)*rstd*gg[e] + bb[e]);
  *(bf16x8*)&out[(size_t)row*DD + lane*8] = *(const bf16x8*)r;
}

// ---------------- weight transpose+cast ----------------
__global__ __launch_bounds__(256) void transpose_cast_kernel(const float* __restrict__ src,
    short* __restrict__ dst, int R, int C){
  __shared__ float tile[32][33];
  size_t off = (size_t)blockIdx.z * R * C;
  src += off; dst += off;
  int c0 = blockIdx.x*32, r0 = blockIdx.y*32;
  int tx = threadIdx.x & 31, ty = threadIdx.x >> 5;
  #pragma unroll
  for (int i=0;i<4;i++) tile[ty + i*8][tx] = src[(size_t)(r0+ty+i*8)*C + c0 + tx];
  __syncthreads();
  #pragma unroll
  for (int i=0;i<4;i++) dst[(size_t)(c0+ty+i*8)*R + r0 + tx] = f2bf(tile[tx][ty+i*8]);
}

// ---------------- plain cast f32 -> bf16 ----------------
__global__ void cast_kernel(const float* __restrict__ in, short* __restrict__ out, int n){
  for (int i = blockIdx.x*blockDim.x + threadIdx.x; i < n; i += gridDim.x*blockDim.x)
    out[i] = f2bf(in[i]);
}

// ---------------- GEMM via global_load_lds, 128x128 tile, BK=64, XCD swizzle ----------------
template<int EPI>
__global__ __launch_bounds__(256) void gemm_dma(const short* __restrict__ A,
    const short* __restrict__ BT, const float* __restrict__ bias, void* __restrict__ C,
    int M, int N, int K)
{
  __shared__ short As[128*64];
  __shared__ short Bs[128*64];
  const int gx = gridDim.x, nwg = gx*gridDim.y;
  int lin = blockIdx.y*gx + blockIdx.x;
  lin = (lin & 7)*(nwg >> 3) + (lin >> 3);
  const int row0 = (lin % gx)*128, col0 = (lin / gx)*128;
  const int t = threadIdx.x, lane = t & 63, w = t >> 6;
  const int wm = w >> 1, wn = w & 1;
  const int rr = lane & 15, g = lane >> 4;
  f32x4 acc[4][4];
  #pragma unroll
  for (int m=0;m<4;m++)
    #pragma unroll
    for (int n=0;n<4;n++) acc[m][n] = (f32x4){0.f,0.f,0.f,0.f};

  const short* aP = A  + (size_t)(row0 + w*32 + (lane>>3))*K + (lane&7)*8;
  const short* bP = BT + (size_t)(col0 + w*32 + (lane>>3))*K + (lane&7)*8;
  short* aL = As + w*2048;
  short* bL = Bs + w*2048;

  for (int kt=0; kt<K; kt+=64){
    __syncthreads();
    #pragma unroll
    for (int i=0;i<4;i++){
      GL2LDS(aP + (size_t)i*8*K + kt, aL + i*512);
      GL2LDS(bP + (size_t)i*8*K + kt, bL + i*512);
    }
    __syncthreads();
    #pragma unroll
    for (int ks=0; ks<2; ks++){
      bf16x8 af[4], bfr[4];
      #pragma unroll
      for (int m=0;m<4;m++) af[m]  = *(const bf16x8*)&As[(wm*64 + m*16 + rr)*64 + ks*32 + g*8];
      #pragma unroll
      for (int n=0;n<4;n++) bfr[n] = *(const bf16x8*)&Bs[(wn*64 + n*16 + rr)*64 + ks*32 + g*8];
      #pragma unroll
      for (int m=0;m<4;m++)
        #pragma unroll
        for (int n=0;n<4;n++)
          acc[m][n] = __builtin_amdgcn_mfma_f32_16x16x32_bf16(af[m], bfr[n], acc[m][n], 0,0,0);
    }
  }
  #pragma unroll
  for (int m=0;m<4;m++){
    #pragma unroll
    for (int n=0;n<4;n++){
      int cg = col0 + wn*64 + n*16 + rr;
      float bv = bias[cg];
      #pragma unroll
      for (int i=0;i<4;i++){
        int rg = row0 + wm*64 + m*16 + g*4 + i;
        float v = acc[m][n][i] + bv;
        size_t idx = (size_t)rg*N + cg;
        if constexpr (EPI==1) ((short*)C)[idx] = f2bf(v);
        else if constexpr (EPI==2) { v = 0.5f*v*(1.0f + erff(v*0.70710678118f)); ((short*)C)[idx] = f2bf(v); }
        else { ((float*)C)[idx] += v; }
      }
    }
  }
}

// ---------------- GEMM 128x64 tile (N=512 GEMMs), residual += ----------------
__global__ __launch_bounds__(256) void gemm_dma_n64(const short* __restrict__ A,
    const short* __restrict__ BT, const float* __restrict__ bias, float* __restrict__ C,
    int M, int N, int K)
{
  __shared__ short As[128*64];
  __shared__ short Bs[64*64];
  const int gx = gridDim.x, nwg = gx*gridDim.y;
  int lin = blockIdx.y*gx + blockIdx.x;
  lin = (lin & 7)*(nwg >> 3) + (lin >> 3);
  const int row0 = (lin % gx)*128, col0 = (lin / gx)*64;
  const int t = threadIdx.x, lane = t & 63, w = t >> 6;
  const int wm = w >> 1, wn = w & 1;
  const int rr = lane & 15, g = lane >> 4;
  f32x4 acc[4][2];
  #pragma unroll
  for (int m=0;m<4;m++)
    #pragma unroll
    for (int n=0;n<2;n++) acc[m][n] = (f32x4){0.f,0.f,0.f,0.f};

  const short* aP = A  + (size_t)(row0 + w*32 + (lane>>3))*K + (lane&7)*8;
  const short* bP = BT + (size_t)(col0 + w*16 + (lane>>3))*K + (lane&7)*8;
  short* aL = As + w*2048;
  short* bL = Bs + w*1024;

  for (int kt=0; kt<K; kt+=64){
    __syncthreads();
    #pragma unroll
    for (int i=0;i<4;i++) GL2LDS(aP + (size_t)i*8*K + kt, aL + i*512);
    #pragma unroll
    for (int i=0;i<2;i++) GL2LDS(bP + (size_t)i*8*K + kt, bL + i*512);
    __syncthreads();
    #pragma unroll
    for (int ks=0; ks<2; ks++){
      bf16x8 af[4], bfr[2];
      #pragma unroll
      for (int m=0;m<4;m++) af[m]  = *(const bf16x8*)&As[(wm*64 + m*16 + rr)*64 + ks*32 + g*8];
      #pragma unroll
      for (int n=0;n<2;n++) bfr[n] = *(const bf16x8*)&Bs[(wn*32 + n*16 + rr)*64 + ks*32 + g*8];
      #pragma unroll
      for (int m=0;m<4;m++)
        #pragma unroll
        for (int n=0;n<2;n++)
          acc[m][n] = __builtin_amdgcn_mfma_f32_16x16x32_bf16(af[m], bfr[n], acc[m][n], 0,0,0);
    }
  }
  #pragma unroll
  for (int m=0;m<4;m++){
    #pragma unroll
    for (int n=0;n<2;n++){
      int cg = col0 + wn*32 + n*16 + rr;
      float bv = bias[cg];
      #pragma unroll
      for (int i=0;i<4;i++){
        int rg = row0 + wm*64 + m*16 + g*4 + i;
        C[(size_t)rg*N + cg] += acc[m][n][i] + bv;
      }
    }
  }
}

// ---------------- small reg-staged GEMM (lm_head) ----------------
template<int BM, int BN>
__global__ __launch_bounds__(256) void gemm_small(const short* __restrict__ A,
    const short* __restrict__ BT, float* __restrict__ C, int M, int N, int K)
{
  constexpr int FM = BM/32, FN = BN/32;
  __shared__ short As[BM][72];
  __shared__ short Bs[BN][72];
  const int row0 = blockIdx.x*BM, col0 = blockIdx.y*BN;
  const int t = threadIdx.x, lane = t & 63, w = t >> 6;
  const int wm = w >> 1, wn = w & 1;
  const int rr = lane & 15, kg = (lane >> 4)*8;
  f32x4 acc[FM][FN];
  #pragma unroll
  for (int m=0;m<FM;m++)
    #pragma unroll
    for (int n=0;n<FN;n++) acc[m][n] = (f32x4){0.f,0.f,0.f,0.f};

  for (int kt=0; kt<K; kt+=64){
    #pragma unroll
    for (int i=0;i<BM/32;i++){
      int cid = t + i*256; int r = cid >> 3; int c = (cid & 7)*8;
      *(bf16x8*)&As[r][c] = *(const bf16x8*)&A[(size_t)(row0+r)*K + kt + c];
    }
    #pragma unroll
    for (int i=0;i<BN/32;i++){
      int cid = t + i*256; int r = cid >> 3; int c = (cid & 7)*8;
      *(bf16x8*)&Bs[r][c] = *(const bf16x8*)&BT[(size_t)(col0+r)*K + kt + c];
    }
    __syncthreads();
    #pragma unroll
    for (int ks=0; ks<2; ks++){
      bf16x8 af[FM], bfr[FN];
      #pragma unroll
      for (int m=0;m<FM;m++) af[m] = *(const bf16x8*)&As[wm*FM*16 + m*16 + rr][ks*32 + kg];
      #pragma unroll
      for (int n=0;n<FN;n++) bfr[n] = *(const bf16x8*)&Bs[wn*FN*16 + n*16 + rr][ks*32 + kg];
      #pragma unroll
      for (int m=0;m<FM;m++)
        #pragma unroll
        for (int n=0;n<FN;n++)
          acc[m][n] = __builtin_amdgcn_mfma_f32_16x16x32_bf16(af[m], bfr[n], acc[m][n], 0,0,0);
    }
    __syncthreads();
  }
  #pragma unroll
  for (int m=0;m<FM;m++)
    #pragma unroll
    for (int n=0;n<FN;n++){
      int cg = col0 + wn*FN*16 + n*16 + rr;
      #pragma unroll
      for (int i=0;i<4;i++){
        int rg = row0 + wm*FM*16 + m*16 + (lane>>4)*4 + i;
        C[(size_t)rg*N + cg] = acc[m][n][i];
      }
    }
}

// ---------------- attention v5: per-tile compute for one q-state ----------------
__device__ __forceinline__ void attn_tile(const short* __restrict__ Kc,
    const short* __restrict__ Vc, const bf16x8* qr, f32x4* oacc,
    float& mrun, float& lpart, int qi, int g, int qloc, bool diag)
{
  f32x4 sacc[4];
  #pragma unroll
  for (int f=0; f<4; f++) sacc[f] = (f32x4){0.f,0.f,0.f,0.f};
  __builtin_amdgcn_s_setprio(1);
  #pragma unroll
  for (int ks=0; ks<2; ks++){
    #pragma unroll
    for (int f=0; f<4; f++){
      bf16x8 kf = *(const bf16x8*)&Kc[(f*16 + qi)*64 + (((ks*4 + g) ^ (qi&7))*8)];
      sacc[f] = __builtin_amdgcn_mfma_f32_16x16x32_bf16(kf, qr[ks], sacc[f], 0,0,0);
    }
  }
  __builtin_amdgcn_s_setprio(0);

  float p[4][4];
  if (diag){
    #pragma unroll
    for (int f=0; f<4; f++)
      #pragma unroll
      for (int i=0; i<4; i++){
        int koffs = f*16 + g*4 + i;
        p[f][i] = (koffs <= qloc) ? sacc[f][i] : -1e30f;
      }
  } else {
    #pragma unroll
    for (int f=0; f<4; f++)
      #pragma unroll
      for (int i=0; i<4; i++) p[f][i] = sacc[f][i];
  }
  float t0 = fmaxf(fmaxf(p[0][0],p[0][1]), fmaxf(p[0][2],p[0][3]));
  float t1 = fmaxf(fmaxf(p[1][0],p[1][1]), fmaxf(p[1][2],p[1][3]));
  float t2 = fmaxf(fmaxf(p[2][0],p[2][1]), fmaxf(p[2][2],p[2][3]));
  float t3 = fmaxf(fmaxf(p[3][0],p[3][1]), fmaxf(p[3][2],p[3][3]));
  float tm = fmaxf(fmaxf(t0,t1), fmaxf(t2,t3));
  tm = fmaxf(tm, __shfl_xor(tm, 16));
  tm = xmax32(tm);
  if (!__all(tm <= mrun + 8.f)){            // defer-max (log2 units)
    float mnew = fmaxf(mrun, tm);
    float corr = ex2(mrun - mnew);
    lpart *= corr;
    #pragma unroll
    for (int mf=0; mf<4; mf++)
      #pragma unroll
      for (int i=0; i<4; i++) oacc[mf][i] *= corr;
    mrun = mnew;
  }
  float ts = 0.f;
  #pragma unroll
  for (int f=0; f<4; f++)
    #pragma unroll
    for (int i=0; i<4; i++){
      float e = ex2(p[f][i] - mrun);
      p[f][i] = e;
      ts += e;
    }
  lpart += ts;                               // per-lane partial; reduced once at end

  __builtin_amdgcn_s_setprio(1);
  #pragma unroll
  for (int w2=0; w2<2; w2++){
    union { unsigned u[4]; bf16x8 v; } bfr;
    bfr.u[0] = cvtpk(p[2*w2  ][0], p[2*w2  ][1]);
    bfr.u[1] = cvtpk(p[2*w2  ][2], p[2*w2  ][3]);
    bfr.u[2] = cvtpk(p[2*w2+1][0], p[2*w2+1][1]);
    bfr.u[3] = cvtpk(p[2*w2+1][2], p[2*w2+1][3]);
    #pragma unroll
    for (int mf=0; mf<4; mf++){
      const short* vp = &Vc[(mf*16 + qi)*72 + w2*32 + g*4];
      union { bf16x4 h[2]; bf16x8 v; } af;
      af.h[0] = *(const bf16x4*)vp;
      af.h[1] = *(const bf16x4*)(vp + 16);
      oacc[mf] = __builtin_amdgcn_mfma_f32_16x16x32_bf16(af.v, bfr.v, oacc[mf], 0,0,0);
    }
  }
  __builtin_amdgcn_s_setprio(0);
}

// ---------------- MFMA flash attention v5 ----------------
// Flat 512-block grid. lin%8 -> XCD; each XCD owns 4 (b,h) pairs (L2 affinity).
// Block handles paired q-tiles (qp, 31-qp): uniform 33 tile-computes.
// K + Vt double-buffered; ONE barrier per tile.
__global__ __launch_bounds__(256) void attn_kernel(const short* __restrict__ qkv, short* __restrict__ o){
  __shared__ __align__(16) char smem[34816];
  short* KsB = (short*)smem;             // 2 x [64][64], chunk-swizzled (chunk ^= row&7)
  short* VtB = (short*)(smem + 16384);   // 2 x Vt[d][k] [64][72]
  float* Osh = (float*)smem;             // [64][65] alias (epilogue only)

  const int lin = blockIdx.x;
  const int xcd = lin & 7, idx = lin >> 3;
  const int bh = xcd*4 + (idx & 3);
  const int qp = idx >> 2;               // 0..15
  const int b = bh >> 3, hh = bh & 7;
  const int ql = qp, qh = 31 - qp;
  const int nt = qh + 1;                 // staged K tiles (17..32)

  const int t = threadIdx.x, lane = t & 63, wid = t >> 6;
  const int g = lane >> 4, qi = lane & 15;
  const int qloc = wid*16 + qi;
  const size_t base = (size_t)b*TT*3*DD + hh*64;

  // Q regs, pre-scaled into exp2 domain
  bf16x8 qL[2], qH[2];
  {
    const float qs = 0.125f * 1.44269504f;
    const short* qpL = qkv + base + (size_t)(ql*64 + qloc)*3*DD + g*8;
    const short* qpH = qkv + base + (size_t)(qh*64 + qloc)*3*DD + g*8;
    qL[0] = *(const bf16x8*)&qpL[0]; qL[1] = *(const bf16x8*)&qpL[32];
    qH[0] = *(const bf16x8*)&qpH[0]; qH[1] = *(const bf16x8*)&qpH[32];
    #pragma unroll
    for (int j=0;j<8;j++){
      qL[0][j] = f2bf(qs * bf2f(qL[0][j]));
      qL[1][j] = f2bf(qs * bf2f(qL[1][j]));
      qH[0][j] = f2bf(qs * bf2f(qH[0][j]));
      qH[1][j] = f2bf(qs * bf2f(qH[1][j]));
    }
  }
  f32x4 oL[4], oH[4];
  #pragma unroll
  for (int mf=0; mf<4; mf++){ oL[mf] = (f32x4){0.f,0.f,0.f,0.f}; oH[mf] = (f32x4){0.f,0.f,0.f,0.f}; }
  float mL = -1e30f, lL = 0.f, mH = -1e30f, lH = 0.f;

  // K DMA: wave wid stages k-rows wid*16+i*8+(lane>>3); src chunk (lane&7)^(lane>>3)
  const short* ksrc = qkv + base + DD + (size_t)(wid*16 + (lane>>3))*3*DD
                      + (((lane&7) ^ (lane>>3))*8);
  // V: thread loads V[vk][vd..], V[vk+1][vd..]
  const int vk = (t & 31)*2, vd = (t >> 5)*8;
  const short* vsrc = qkv + base + 2*DD + (size_t)vk*3*DD + vd;

  // ---- prologue: K(0) DMA, V(0)+V(1) regs, write Vt(0) ----
  GL2LDS(ksrc, KsB + wid*1024);
  GL2LDS(ksrc + (size_t)8*3*DD, KsB + wid*1024 + 512);
  bf16x8 v0a = *(const bf16x8*)vsrc;
  bf16x8 v0b = *(const bf16x8*)(vsrc + 3*DD);
  bf16x8 vLoA = *(const bf16x8*)(vsrc + (size_t)64*3*DD);
  bf16x8 vLoB = *(const bf16x8*)(vsrc + (size_t)64*3*DD + 3*DD);
  asm volatile("s_waitcnt vmcnt(0)" ::: "memory");
  #pragma unroll
  for (int e=0;e<8;e++)
    *(unsigned*)&VtB[(vd+e)*72 + vk] =
        (unsigned)(unsigned short)v0a[e] | ((unsigned)(unsigned short)v0b[e] << 16);

  for (int kb = 0; kb < nt; kb++){
    // single barrier: K(kb) DMA'd, Vt(kb) written, V(kb+1) regs loaded -- all visible
    asm volatile("s_waitcnt vmcnt(0) lgkmcnt(0)\n\ts_barrier" ::: "memory");
    bf16x8 vHiA = vLoA, vHiB = vLoB;
    if (kb+1 < nt){
      const size_t koff = (size_t)(kb+1)*64*3*DD;
      short* kd = KsB + ((kb+1)&1)*4096 + wid*1024;
      GL2LDS(ksrc + koff, kd);
      GL2LDS(ksrc + koff + (size_t)8*3*DD, kd + 512);
      short* Vn = VtB + ((kb+1)&1)*4608;
      #pragma unroll
      for (int e=0;e<8;e++)
        *(unsigned*)&Vn[(vd+e)*72 + vk] =
            (unsigned)(unsigned short)vLoA[e] | ((unsigned)(unsigned short)vLoB[e] << 16);
    }
    if (kb+2 < nt){
      const size_t koff2 = (size_t)(kb+2)*64*3*DD;
      vHiA = *(const bf16x8*)(vsrc + koff2);
      vHiB = *(const bf16x8*)(vsrc + koff2 + 3*DD);
    }
    const short* Kc = KsB + (kb&1)*4096;
    const short* Vc = VtB + (kb&1)*4608;

    attn_tile(Kc, Vc, qH, oH, mH, lH, qi, g, qloc, kb == nt-1);
    if (kb <= ql)
      attn_tile(Kc, Vc, qL, oL, mL, lL, qi, g, qloc, kb == ql);

    vLoA = vHiA; vLoB = vHiB;
  }

  // ---- reduce l across the 4 g-lanes (once) ----
  lL += __shfl_xor(lL, 16); lL = xadd32(lL);
  lH += __shfl_xor(lH, 16); lH = xadd32(lH);

  // ---- epilogue: two q-tiles through aliased Osh ----
  const int orow = t >> 2, cc = (t & 3) * 16;
  #pragma unroll
  for (int s=0; s<2; s++){
    const f32x4* oacc = s ? oH : oL;
    const float inv = 1.f / (s ? lH : lL);
    const int q0 = (s ? qh : ql) * 64;
    __syncthreads();
    #pragma unroll
    for (int mf=0; mf<4; mf++)
      #pragma unroll
      for (int i=0; i<4; i++)
        Osh[qloc*65 + mf*16 + g*4 + i] = oacc[mf][i] * inv;
    __syncthreads();
    short tmp[16];
    #pragma unroll
    for (int e=0; e<16; e++) tmp[e] = f2bf(Osh[orow*65 + cc + e]);
    short* op = o + ((size_t)b*TT + q0 + orow)*DD + hh*64 + cc;
    *(bf16x8*)&op[0] = *(const bf16x8*)&tmp[0];
    *(bf16x8*)&op[8] = *(const bf16x8*)&tmp[8];
  }
}

extern "C" void kernel_launch(void* const* d_in, const int* in_sizes, int n_in,
                              void* d_out, int out_size, void* d_ws, size_t ws_size,
                              hipStream_t stream) {
  const int*   x      = (const int*)d_in[0];
  const float* tok    = (const float*)d_in[1];
  const float* pos    = (const float*)d_in[2];
  const float* attn_w = (const float*)d_in[3];
  const float* attn_b = (const float*)d_in[4];
  const float* proj_w = (const float*)d_in[5];
  const float* proj_b = (const float*)d_in[6];
  const float* ln1_g  = (const float*)d_in[7];
  const float* ln1_b  = (const float*)d_in[8];
  const float* ln2_g  = (const float*)d_in[9];
  const float* ln2_b  = (const float*)d_in[10];
  const float* ff1_w  = (const float*)d_in[11];
  const float* ff1_b  = (const float*)d_in[12];
  const float* ff2_w  = (const float*)d_in[13];
  const float* ff2_b  = (const float*)d_in[14];
  const float* lnf_g  = (const float*)d_in[15];
  const float* lnf_b  = (const float*)d_in[16];

  char* p = (char*)d_ws;
  float* h   = (float*)p; p += (size_t)ROWS*DD*4;
  short* hn  = (short*)p; p += (size_t)ROWS*DD*2;
  short* qkv = (short*)p; p += (size_t)ROWS*3*DD*2;
  short* ob  = (short*)p; p += (size_t)ROWS*DD*2;
  short* ffb = (short*)p; p += (size_t)ROWS*FFD*2;
  short* awT = (short*)p; p += (size_t)LL*3*DD*DD*2;
  short* pwT = (short*)p; p += (size_t)LL*DD*DD*2;
  short* f1T = (short*)p; p += (size_t)LL*FFD*DD*2;
  short* f2T = (short*)p; p += (size_t)LL*DD*FFD*2;
  short* lmT = (short*)p; p += (size_t)VV*DD*2;

  transpose_cast_kernel<<<dim3(48,16,8),256,0,stream>>>(attn_w, awT, DD, 3*DD);
  transpose_cast_kernel<<<dim3(16,16,8),256,0,stream>>>(proj_w, pwT, DD, DD);
  transpose_cast_kernel<<<dim3(64,16,8),256,0,stream>>>(ff1_w, f1T, DD, FFD);
  transpose_cast_kernel<<<dim3(16,64,8),256,0,stream>>>(ff2_w, f2T, FFD, DD);
  cast_kernel<<<128,256,0,stream>>>(tok, lmT, VV*DD);
  embed_kernel<<<ROWS,128,0,stream>>>(x, tok, pos, h);

  for (int l=0;l<LL;l++){
    ln_kernel<<<ROWS/4,256,0,stream>>>(h, ln1_g + l*DD, ln1_b + l*DD, hn);
    gemm_dma<1><<<dim3(ROWS/128, (3*DD)/128),256,0,stream>>>(
        hn, awT + (size_t)l*3*DD*DD, attn_b + (size_t)l*3*DD, qkv, ROWS, 3*DD, DD);
    attn_kernel<<<512,256,0,stream>>>(qkv, ob);
    gemm_dma_n64<<<dim3(ROWS/128, DD/64),256,0,stream>>>(
        ob, pwT + (size_t)l*DD*DD, proj_b + (size_t)l*DD, h, ROWS, DD, DD);
    ln_kernel<<<ROWS/4,256,0,stream>>>(h, ln2_g + l*DD, ln2_b + l*DD, hn);
    gemm_dma<2><<<dim3(ROWS/128, FFD/128),256,0,stream>>>(
        hn, f1T + (size_t)l*FFD*DD, ff1_b + (size_t)l*FFD, ffb, ROWS, FFD, DD);
    gemm_dma_n64<<<dim3(ROWS/128, DD/64),256,0,stream>>>(
        ffb, f2T + (size_t)l*DD*FFD, ff2_b + (size_t)l*DD, h, ROWS, DD, FFD);
  }
  ln_kernel<<<ROWS/4,256,0,stream>>>(h, lnf_g, lnf_b, hn);
  gemm_small<64,64><<<dim3(ROWS/64, VV/64),256,0,stream>>>(
      hn, lmT, (float*)d_out, ROWS, VV, DD);
}

// Round 9
// 1572.482 us; speedup vs baseline: 10.4426x; 1.0449x over previous
//
#include <hip/hip_runtime.h>

#define TT 2048
#define BB 4
#define DD 512
#define HH 8
#define LL 8
#define FFD 2048
#define VV 256
#define ROWS (BB*TT)

typedef short bf16x4 __attribute__((ext_vector_type(4)));
typedef short bf16x8 __attribute__((ext_vector_type(8)));
typedef float f32x4 __attribute__((ext_vector_type(4)));

#define GL2LDS(gp, lp) __builtin_amdgcn_global_load_lds( \
    (const __attribute__((address_space(1))) unsigned*)(gp), \
    (__attribute__((address_space(3))) unsigned*)(lp), 16, 0, 0)

__device__ __forceinline__ float bf2f(short s){
  union { unsigned u; float f; } x; x.u = ((unsigned)(unsigned short)s) << 16; return x.f;
}
__device__ __forceinline__ short f2bf(float f){
  union { float f; unsigned u; } x; x.f = f;
  unsigned r = (x.u + 0x7fffu + ((x.u >> 16) & 1u)) >> 16;
  return (short)(unsigned short)r;
}
__device__ __forceinline__ float ex2(float x){
  float r; asm("v_exp_f32 %0, %1" : "=v"(r) : "v"(x)); return r;
}
__device__ __forceinline__ unsigned cvtpk(float lo, float hi){
  unsigned r; asm("v_cvt_pk_bf16_f32 %0, %1, %2" : "=v"(r) : "v"(lo), "v"(hi)); return r;
}
__device__ __forceinline__ float xmax32(float x){ return fmaxf(x, __shfl_xor(x, 32)); }
__device__ __forceinline__ float xadd32(float x){ return x + __shfl_xor(x, 32); }

// ---------------- embedding ----------------
__global__ __launch_bounds__(128) void embed_kernel(const int* __restrict__ x,
    const float* __restrict__ tok, const float* __restrict__ pos, float* __restrict__ h){
  int row = blockIdx.x;
  int t = row & (TT-1);
  int id = x[row];
  const float4 a = *(const float4*)&tok[(size_t)id*DD + threadIdx.x*4];
  const float4 p = *(const float4*)&pos[(size_t)t*DD + threadIdx.x*4];
  float4 r; r.x=a.x+p.x; r.y=a.y+p.y; r.z=a.z+p.z; r.w=a.w+p.w;
  *(float4*)&h[(size_t)row*DD + threadIdx.x*4] = r;
}

// ---------------- LayerNorm: one wave per row ----------------
__global__ __launch_bounds__(256) void ln_kernel(const float* __restrict__ xx,
    const float* __restrict__ gw, const float* __restrict__ bw, short* __restrict__ out){
  const int lane = threadIdx.x & 63, w = threadIdx.x >> 6;
  const int row = blockIdx.x*4 + w;
  const float* xp = xx + (size_t)row*DD + lane*8;
  float4 a = *(const float4*)xp, c = *(const float4*)(xp+4);
  float xv[8] = {a.x,a.y,a.z,a.w,c.x,c.y,c.z,c.w};
  float s1 = 0.f, s2 = 0.f;
  #pragma unroll
  for (int e=0;e<8;e++){ s1 += xv[e]; s2 += xv[e]*xv[e]; }
  #pragma unroll
  for (int off=1; off<64; off<<=1){
    s1 += __shfl_xor(s1, off);
    s2 += __shfl_xor(s2, off);
  }
  const float m = s1 * (1.0f/DD);
  const float rstd = rsqrtf(s2*(1.0f/DD) - m*m + 1e-5f);
  const float4 g0 = *(const float4*)(gw + lane*8), g1 = *(const float4*)(gw + lane*8 + 4);
  const float4 b0 = *(const float4*)(bw + lane*8), b1 = *(const float4*)(bw + lane*8 + 4);
  float gg[8] = {g0.x,g0.y,g0.z,g0.w,g1.x,g1.y,g1.z,g1.w};
  float bb[8] = {b0.x,b0.y,b0.z,b0.w,b1.x,b1.y,b1.z,b1.w};
  short r[8];
  #pragma unroll
  for (int e=0;e<8;e++) r[e] = f2bf((xv[e]-m)*rstd*gg[e] + bb[e]);
  *(bf16x8*)&out[(size_t)row*DD + lane*8] = *(const bf16x8*)r;
}

// ---------------- weight transpose+cast ----------------
__global__ __launch_bounds__(256) void transpose_cast_kernel(const float* __restrict__ src,
    short* __restrict__ dst, int R, int C){
  __shared__ float tile[32][33];
  size_t off = (size_t)blockIdx.z * R * C;
  src += off; dst += off;
  int c0 = blockIdx.x*32, r0 = blockIdx.y*32;
  int tx = threadIdx.x & 31, ty = threadIdx.x >> 5;
  #pragma unroll
  for (int i=0;i<4;i++) tile[ty + i*8][tx] = src[(size_t)(r0+ty+i*8)*C + c0 + tx];
  __syncthreads();
  #pragma unroll
  for (int i=0;i<4;i++) dst[(size_t)(c0+ty+i*8)*R + r0 + tx] = f2bf(tile[tx][ty+i*8]);
}

// ---------------- plain cast f32 -> bf16 ----------------
__global__ void cast_kernel(const float* __restrict__ in, short* __restrict__ out, int n){
  for (int i = blockIdx.x*blockDim.x + threadIdx.x; i < n; i += gridDim.x*blockDim.x)
    out[i] = f2bf(in[i]);
}

// row-band XCD swizzle: XCD x owns row-tiles [x*gx/8, ...) x all col-tiles.
// requires gx%8==0 and nwg%8==0.
__device__ __forceinline__ void xcd_rowband(int gx, int gy, int& rowt, int& colt){
  int lin = blockIdx.y*gx + blockIdx.x;
  int x = lin & 7, j = lin >> 3;
  int jd = j / gy;
  rowt = x*(gx >> 3) + jd;
  colt = j - jd*gy;
}

// ---------------- GEMM, 128x128 tile, dbuf LDS + single barrier/iter ----------------
// EPI: 1 = +bias -> bf16; 2 = +bias,GELU -> bf16; 3 = +bias, residual += into f32
template<int EPI>
__global__ __launch_bounds__(256) void gemm_dma(const short* __restrict__ A,
    const short* __restrict__ BT, const float* __restrict__ bias, void* __restrict__ C,
    int M, int N, int K)
{
  __shared__ short As[2][128*64];
  __shared__ short Bs[2][128*64];
  int rowt, colt;
  xcd_rowband(gridDim.x, gridDim.y, rowt, colt);
  const int row0 = rowt*128, col0 = colt*128;
  const int t = threadIdx.x, lane = t & 63, w = t >> 6;
  const int wm = w >> 1, wn = w & 1;
  const int rr = lane & 15, g = lane >> 4;
  f32x4 acc[4][4];
  #pragma unroll
  for (int m=0;m<4;m++)
    #pragma unroll
    for (int n=0;n<4;n++) acc[m][n] = (f32x4){0.f,0.f,0.f,0.f};

  const short* aP = A  + (size_t)(row0 + w*32 + (lane>>3))*K + (lane&7)*8;
  const short* bP = BT + (size_t)(col0 + w*32 + (lane>>3))*K + (lane&7)*8;

  const int nk = K >> 6;
  // prologue: stage K-tile 0 into buf0
  #pragma unroll
  for (int i=0;i<4;i++){
    GL2LDS(aP + (size_t)i*8*K, &As[0][w*2048 + i*512]);
    GL2LDS(bP + (size_t)i*8*K, &Bs[0][w*2048 + i*512]);
  }
  for (int kt=0; kt<nk; kt++){
    // K(kt) landed (issued a full iter ago); all reads of the other buf done
    asm volatile("s_waitcnt vmcnt(0) lgkmcnt(0)\n\ts_barrier" ::: "memory");
    if (kt+1 < nk){
      const int ko = (kt+1) << 6, nb = (kt+1) & 1;
      #pragma unroll
      for (int i=0;i<4;i++){
        GL2LDS(aP + (size_t)i*8*K + ko, &As[nb][w*2048 + i*512]);
        GL2LDS(bP + (size_t)i*8*K + ko, &Bs[nb][w*2048 + i*512]);
      }
    }
    const short* Ac = As[kt&1];
    const short* Bc = Bs[kt&1];
    #pragma unroll
    for (int ks=0; ks<2; ks++){
      bf16x8 af[4], bfr[4];
      #pragma unroll
      for (int m=0;m<4;m++) af[m]  = *(const bf16x8*)&Ac[(wm*64 + m*16 + rr)*64 + ks*32 + g*8];
      #pragma unroll
      for (int n=0;n<4;n++) bfr[n] = *(const bf16x8*)&Bc[(wn*64 + n*16 + rr)*64 + ks*32 + g*8];
      #pragma unroll
      for (int m=0;m<4;m++)
        #pragma unroll
        for (int n=0;n<4;n++)
          acc[m][n] = __builtin_amdgcn_mfma_f32_16x16x32_bf16(af[m], bfr[n], acc[m][n], 0,0,0);
    }
  }
  #pragma unroll
  for (int m=0;m<4;m++){
    #pragma unroll
    for (int n=0;n<4;n++){
      int cg = col0 + wn*64 + n*16 + rr;
      float bv = bias[cg];
      #pragma unroll
      for (int i=0;i<4;i++){
        int rg = row0 + wm*64 + m*16 + g*4 + i;
        float v = acc[m][n][i] + bv;
        size_t idx = (size_t)rg*N + cg;
        if constexpr (EPI==1) ((short*)C)[idx] = f2bf(v);
        else if constexpr (EPI==2) { v = 0.5f*v*(1.0f + erff(v*0.70710678118f)); ((short*)C)[idx] = f2bf(v); }
        else { ((float*)C)[idx] += v; }
      }
    }
  }
}

// ---------------- GEMM 128x64 tile (N=512 GEMMs), residual +=; 2-barrier (control) ----------------
__global__ __launch_bounds__(256) void gemm_dma_n64(const short* __restrict__ A,
    const short* __restrict__ BT, const float* __restrict__ bias, float* __restrict__ C,
    int M, int N, int K)
{
  __shared__ short As[128*64];
  __shared__ short Bs[64*64];
  int rowt, colt;
  xcd_rowband(gridDim.x, gridDim.y, rowt, colt);
  const int row0 = rowt*128, col0 = colt*64;
  const int t = threadIdx.x, lane = t & 63, w = t >> 6;
  const int wm = w >> 1, wn = w & 1;
  const int rr = lane & 15, g = lane >> 4;
  f32x4 acc[4][2];
  #pragma unroll
  for (int m=0;m<4;m++)
    #pragma unroll
    for (int n=0;n<2;n++) acc[m][n] = (f32x4){0.f,0.f,0.f,0.f};

  const short* aP = A  + (size_t)(row0 + w*32 + (lane>>3))*K + (lane&7)*8;
  const short* bP = BT + (size_t)(col0 + w*16 + (lane>>3))*K + (lane&7)*8;
  short* aL = As + w*2048;
  short* bL = Bs + w*1024;

  for (int kt=0; kt<K; kt+=64){
    __syncthreads();
    #pragma unroll
    for (int i=0;i<4;i++) GL2LDS(aP + (size_t)i*8*K + kt, aL + i*512);
    #pragma unroll
    for (int i=0;i<2;i++) GL2LDS(bP + (size_t)i*8*K + kt, bL + i*512);
    __syncthreads();
    #pragma unroll
    for (int ks=0; ks<2; ks++){
      bf16x8 af[4], bfr[2];
      #pragma unroll
      for (int m=0;m<4;m++) af[m]  = *(const bf16x8*)&As[(wm*64 + m*16 + rr)*64 + ks*32 + g*8];
      #pragma unroll
      for (int n=0;n<2;n++) bfr[n] = *(const bf16x8*)&Bs[(wn*32 + n*16 + rr)*64 + ks*32 + g*8];
      #pragma unroll
      for (int m=0;m<4;m++)
        #pragma unroll
        for (int n=0;n<2;n++)
          acc[m][n] = __builtin_amdgcn_mfma_f32_16x16x32_bf16(af[m], bfr[n], acc[m][n], 0,0,0);
    }
  }
  #pragma unroll
  for (int m=0;m<4;m++){
    #pragma unroll
    for (int n=0;n<2;n++){
      int cg = col0 + wn*32 + n*16 + rr;
      float bv = bias[cg];
      #pragma unroll
      for (int i=0;i<4;i++){
        int rg = row0 + wm*64 + m*16 + g*4 + i;
        C[(size_t)rg*N + cg] += acc[m][n][i] + bv;
      }
    }
  }
}

// ---------------- small reg-staged GEMM (lm_head) ----------------
template<int BM, int BN>
__global__ __launch_bounds__(256) void gemm_small(const short* __restrict__ A,
    const short* __restrict__ BT, float* __restrict__ C, int M, int N, int K)
{
  constexpr int FM = BM/32, FN = BN/32;
  __shared__ short As[BM][72];
  __shared__ short Bs[BN][72];
  const int row0 = blockIdx.x*BM, col0 = blockIdx.y*BN;
  const int t = threadIdx.x, lane = t & 63, w = t >> 6;
  const int wm = w >> 1, wn = w & 1;
  const int rr = lane & 15, kg = (lane >> 4)*8;
  f32x4 acc[FM][FN];
  #pragma unroll
  for (int m=0;m<FM;m++)
    #pragma unroll
    for (int n=0;n<FN;n++) acc[m][n] = (f32x4){0.f,0.f,0.f,0.f};

  for (int kt=0; kt<K; kt+=64){
    #pragma unroll
    for (int i=0;i<BM/32;i++){
      int cid = t + i*256; int r = cid >> 3; int c = (cid & 7)*8;
      *(bf16x8*)&As[r][c] = *(const bf16x8*)&A[(size_t)(row0+r)*K + kt + c];
    }
    #pragma unroll
    for (int i=0;i<BN/32;i++){
      int cid = t + i*256; int r = cid >> 3; int c = (cid & 7)*8;
      *(bf16x8*)&Bs[r][c] = *(const bf16x8*)&BT[(size_t)(col0+r)*K + kt + c];
    }
    __syncthreads();
    #pragma unroll
    for (int ks=0; ks<2; ks++){
      bf16x8 af[FM], bfr[FN];
      #pragma unroll
      for (int m=0;m<FM;m++) af[m] = *(const bf16x8*)&As[wm*FM*16 + m*16 + rr][ks*32 + kg];
      #pragma unroll
      for (int n=0;n<FN;n++) bfr[n] = *(const bf16x8*)&Bs[wn*FN*16 + n*16 + rr][ks*32 + kg];
      #pragma unroll
      for (int m=0;m<FM;m++)
        #pragma unroll
        for (int n=0;n<FN;n++)
          acc[m][n] = __builtin_amdgcn_mfma_f32_16x16x32_bf16(af[m], bfr[n], acc[m][n], 0,0,0);
    }
    __syncthreads();
  }
  #pragma unroll
  for (int m=0;m<FM;m++)
    #pragma unroll
    for (int n=0;n<FN;n++){
      int cg = col0 + wn*FN*16 + n*16 + rr;
      #pragma unroll
      for (int i=0;i<4;i++){
        int rg = row0 + wm*FM*16 + m*16 + (lane>>4)*4 + i;
        C[(size_t)rg*N + cg] = acc[m][n][i];
      }
    }
}

// ---------------- attention v5: per-tile compute for one q-state ----------------
__device__ __forceinline__ void attn_tile(const short* __restrict__ Kc,
    const short* __restrict__ Vc, const bf16x8* qr, f32x4* oacc,
    float& mrun, float& lpart, int qi, int g, int qloc, bool diag)
{
  f32x4 sacc[4];
  #pragma unroll
  for (int f=0; f<4; f++) sacc[f] = (f32x4){0.f,0.f,0.f,0.f};
  __builtin_amdgcn_s_setprio(1);
  #pragma unroll
  for (int ks=0; ks<2; ks++){
    #pragma unroll
    for (int f=0; f<4; f++){
      bf16x8 kf = *(const bf16x8*)&Kc[(f*16 + qi)*64 + (((ks*4 + g) ^ (qi&7))*8)];
      sacc[f] = __builtin_amdgcn_mfma_f32_16x16x32_bf16(kf, qr[ks], sacc[f], 0,0,0);
    }
  }
  __builtin_amdgcn_s_setprio(0);

  float p[4][4];
  if (diag){
    #pragma unroll
    for (int f=0; f<4; f++)
      #pragma unroll
      for (int i=0; i<4; i++){
        int koffs = f*16 + g*4 + i;
        p[f][i] = (koffs <= qloc) ? sacc[f][i] : -1e30f;
      }
  } else {
    #pragma unroll
    for (int f=0; f<4; f++)
      #pragma unroll
      for (int i=0; i<4; i++) p[f][i] = sacc[f][i];
  }
  float t0 = fmaxf(fmaxf(p[0][0],p[0][1]), fmaxf(p[0][2],p[0][3]));
  float t1 = fmaxf(fmaxf(p[1][0],p[1][1]), fmaxf(p[1][2],p[1][3]));
  float t2 = fmaxf(fmaxf(p[2][0],p[2][1]), fmaxf(p[2][2],p[2][3]));
  float t3 = fmaxf(fmaxf(p[3][0],p[3][1]), fmaxf(p[3][2],p[3][3]));
  float tm = fmaxf(fmaxf(t0,t1), fmaxf(t2,t3));
  tm = fmaxf(tm, __shfl_xor(tm, 16));
  tm = xmax32(tm);
  if (!__all(tm <= mrun + 8.f)){            // defer-max (log2 units)
    float mnew = fmaxf(mrun, tm);
    float corr = ex2(mrun - mnew);
    lpart *= corr;
    #pragma unroll
    for (int mf=0; mf<4; mf++)
      #pragma unroll
      for (int i=0; i<4; i++) oacc[mf][i] *= corr;
    mrun = mnew;
  }
  float ts = 0.f;
  #pragma unroll
  for (int f=0; f<4; f++)
    #pragma unroll
    for (int i=0; i<4; i++){
      float e = ex2(p[f][i] - mrun);
      p[f][i] = e;
      ts += e;
    }
  lpart += ts;                               // per-lane partial; reduced once at end

  __builtin_amdgcn_s_setprio(1);
  #pragma unroll
  for (int w2=0; w2<2; w2++){
    union { unsigned u[4]; bf16x8 v; } bfr;
    bfr.u[0] = cvtpk(p[2*w2  ][0], p[2*w2  ][1]);
    bfr.u[1] = cvtpk(p[2*w2  ][2], p[2*w2  ][3]);
    bfr.u[2] = cvtpk(p[2*w2+1][0], p[2*w2+1][1]);
    bfr.u[3] = cvtpk(p[2*w2+1][2], p[2*w2+1][3]);
    #pragma unroll
    for (int mf=0; mf<4; mf++){
      const short* vp = &Vc[(mf*16 + qi)*72 + w2*32 + g*4];
      union { bf16x4 h[2]; bf16x8 v; } af;
      af.h[0] = *(const bf16x4*)vp;
      af.h[1] = *(const bf16x4*)(vp + 16);
      oacc[mf] = __builtin_amdgcn_mfma_f32_16x16x32_bf16(af.v, bfr.v, oacc[mf], 0,0,0);
    }
  }
  __builtin_amdgcn_s_setprio(0);
}

// ---------------- MFMA flash attention v5 ----------------
__global__ __launch_bounds__(256) void attn_kernel(const short* __restrict__ qkv, short* __restrict__ o){
  __shared__ __align__(16) char smem[34816];
  short* KsB = (short*)smem;             // 2 x [64][64], chunk-swizzled (chunk ^= row&7)
  short* VtB = (short*)(smem + 16384);   // 2 x Vt[d][k] [64][72]
  float* Osh = (float*)smem;             // [64][65] alias (epilogue only)

  const int lin = blockIdx.x;
  const int xcd = lin & 7, idx = lin >> 3;
  const int bh = xcd*4 + (idx & 3);
  const int qp = idx >> 2;               // 0..15
  const int b = bh >> 3, hh = bh & 7;
  const int ql = qp, qh = 31 - qp;
  const int nt = qh + 1;

  const int t = threadIdx.x, lane = t & 63, wid = t >> 6;
  const int g = lane >> 4, qi = lane & 15;
  const int qloc = wid*16 + qi;
  const size_t base = (size_t)b*TT*3*DD + hh*64;

  bf16x8 qL[2], qH[2];
  {
    const float qs = 0.125f * 1.44269504f;
    const short* qpL = qkv + base + (size_t)(ql*64 + qloc)*3*DD + g*8;
    const short* qpH = qkv + base + (size_t)(qh*64 + qloc)*3*DD + g*8;
    qL[0] = *(const bf16x8*)&qpL[0]; qL[1] = *(const bf16x8*)&qpL[32];
    qH[0] = *(const bf16x8*)&qpH[0]; qH[1] = *(const bf16x8*)&qpH[32];
    #pragma unroll
    for (int j=0;j<8;j++){
      qL[0][j] = f2bf(qs * bf2f(qL[0][j]));
      qL[1][j] = f2bf(qs * bf2f(qL[1][j]));
      qH[0][j] = f2bf(qs * bf2f(qH[0][j]));
      qH[1][j] = f2bf(qs * bf2f(qH[1][j]));
    }
  }
  f32x4 oL[4], oH[4];
  #pragma unroll
  for (int mf=0; mf<4; mf++){ oL[mf] = (f32x4){0.f,0.f,0.f,0.f}; oH[mf] = (f32x4){0.f,0.f,0.f,0.f}; }
  float mL = -1e30f, lL = 0.f, mH = -1e30f, lH = 0.f;

  const short* ksrc = qkv + base + DD + (size_t)(wid*16 + (lane>>3))*3*DD
                      + (((lane&7) ^ (lane>>3))*8);
  const int vk = (t & 31)*2, vd = (t >> 5)*8;
  const short* vsrc = qkv + base + 2*DD + (size_t)vk*3*DD + vd;

  GL2LDS(ksrc, KsB + wid*1024);
  GL2LDS(ksrc + (size_t)8*3*DD, KsB + wid*1024 + 512);
  bf16x8 v0a = *(const bf16x8*)vsrc;
  bf16x8 v0b = *(const bf16x8*)(vsrc + 3*DD);
  bf16x8 vLoA = *(const bf16x8*)(vsrc + (size_t)64*3*DD);
  bf16x8 vLoB = *(const bf16x8*)(vsrc + (size_t)64*3*DD + 3*DD);
  asm volatile("s_waitcnt vmcnt(0)" ::: "memory");
  #pragma unroll
  for (int e=0;e<8;e++)
    *(unsigned*)&VtB[(vd+e)*72 + vk] =
        (unsigned)(unsigned short)v0a[e] | ((unsigned)(unsigned short)v0b[e] << 16);

  for (int kb = 0; kb < nt; kb++){
    asm volatile("s_waitcnt vmcnt(0) lgkmcnt(0)\n\ts_barrier" ::: "memory");
    bf16x8 vHiA = vLoA, vHiB = vLoB;
    if (kb+1 < nt){
      const size_t koff = (size_t)(kb+1)*64*3*DD;
      short* kd = KsB + ((kb+1)&1)*4096 + wid*1024;
      GL2LDS(ksrc + koff, kd);
      GL2LDS(ksrc + koff + (size_t)8*3*DD, kd + 512);
      short* Vn = VtB + ((kb+1)&1)*4608;
      #pragma unroll
      for (int e=0;e<8;e++)
        *(unsigned*)&Vn[(vd+e)*72 + vk] =
            (unsigned)(unsigned short)vLoA[e] | ((unsigned)(unsigned short)vLoB[e] << 16);
    }
    if (kb+2 < nt){
      const size_t koff2 = (size_t)(kb+2)*64*3*DD;
      vHiA = *(const bf16x8*)(vsrc + koff2);
      vHiB = *(const bf16x8*)(vsrc + koff2 + 3*DD);
    }
    const short* Kc = KsB + (kb&1)*4096;
    const short* Vc = VtB + (kb&1)*4608;

    attn_tile(Kc, Vc, qH, oH, mH, lH, qi, g, qloc, kb == nt-1);
    if (kb <= ql)
      attn_tile(Kc, Vc, qL, oL, mL, lL, qi, g, qloc, kb == ql);

    vLoA = vHiA; vLoB = vHiB;
  }

  lL += __shfl_xor(lL, 16); lL = xadd32(lL);
  lH += __shfl_xor(lH, 16); lH = xadd32(lH);

  const int orow = t >> 2, cc = (t & 3) * 16;
  #pragma unroll
  for (int s=0; s<2; s++){
    const f32x4* oacc = s ? oH : oL;
    const float inv = 1.f / (s ? lH : lL);
    const int q0 = (s ? qh : ql) * 64;
    __syncthreads();
    #pragma unroll
    for (int mf=0; mf<4; mf++)
      #pragma unroll
      for (int i=0; i<4; i++)
        Osh[qloc*65 + mf*16 + g*4 + i] = oacc[mf][i] * inv;
    __syncthreads();
    short tmp[16];
    #pragma unroll
    for (int e=0; e<16; e++) tmp[e] = f2bf(Osh[orow*65 + cc + e]);
    short* op = o + ((size_t)b*TT + q0 + orow)*DD + hh*64 + cc;
    *(bf16x8*)&op[0] = *(const bf16x8*)&tmp[0];
    *(bf16x8*)&op[8] = *(const bf16x8*)&tmp[8];
  }
}

extern "C" void kernel_launch(void* const* d_in, const int* in_sizes, int n_in,
                              void* d_out, int out_size, void* d_ws, size_t ws_size,
                              hipStream_t stream) {
  const int*   x      = (const int*)d_in[0];
  const float* tok    = (const float*)d_in[1];
  const float* pos    = (const float*)d_in[2];
  const float* attn_w = (const float*)d_in[3];
  const float* attn_b = (const float*)d_in[4];
  const float* proj_w = (const float*)d_in[5];
  const float* proj_b = (const float*)d_in[6];
  const float* ln1_g  = (const float*)d_in[7];
  const float* ln1_b  = (const float*)d_in[8];
  const float* ln2_g  = (const float*)d_in[9];
  const float* ln2_b  = (const float*)d_in[10];
  const float* ff1_w  = (const float*)d_in[11];
  const float* ff1_b  = (const float*)d_in[12];
  const float* ff2_w  = (const float*)d_in[13];
  const float* ff2_b  = (const float*)d_in[14];
  const float* lnf_g  = (const float*)d_in[15];
  const float* lnf_b  = (const float*)d_in[16];

  char* p = (char*)d_ws;
  float* h   = (float*)p; p += (size_t)ROWS*DD*4;
  short* hn  = (short*)p; p += (size_t)ROWS*DD*2;
  short* qkv = (short*)p; p += (size_t)ROWS*3*DD*2;
  short* ob  = (short*)p; p += (size_t)ROWS*DD*2;
  short* ffb = (short*)p; p += (size_t)ROWS*FFD*2;
  short* awT = (short*)p; p += (size_t)LL*3*DD*DD*2;
  short* pwT = (short*)p; p += (size_t)LL*DD*DD*2;
  short* f1T = (short*)p; p += (size_t)LL*FFD*DD*2;
  short* f2T = (short*)p; p += (size_t)LL*DD*FFD*2;
  short* lmT = (short*)p; p += (size_t)VV*DD*2;

  transpose_cast_kernel<<<dim3(48,16,8),256,0,stream>>>(attn_w, awT, DD, 3*DD);
  transpose_cast_kernel<<<dim3(16,16,8),256,0,stream>>>(proj_w, pwT, DD, DD);
  transpose_cast_kernel<<<dim3(64,16,8),256,0,stream>>>(ff1_w, f1T, DD, FFD);
  transpose_cast_kernel<<<dim3(16,64,8),256,0,stream>>>(ff2_w, f2T, FFD, DD);
  cast_kernel<<<128,256,0,stream>>>(tok, lmT, VV*DD);
  embed_kernel<<<ROWS,128,0,stream>>>(x, tok, pos, h);

  for (int l=0;l<LL;l++){
    ln_kernel<<<ROWS/4,256,0,stream>>>(h, ln1_g + l*DD, ln1_b + l*DD, hn);
    gemm_dma<1><<<dim3(ROWS/128, (3*DD)/128),256,0,stream>>>(
        hn, awT + (size_t)l*3*DD*DD, attn_b + (size_t)l*3*DD, qkv, ROWS, 3*DD, DD);
    attn_kernel<<<512,256,0,stream>>>(qkv, ob);
    gemm_dma_n64<<<dim3(ROWS/128, DD/64),256,0,stream>>>(
        ob, pwT + (size_t)l*DD*DD, proj_b + (size_t)l*DD, h, ROWS, DD, DD);
    ln_kernel<<<ROWS/4,256,0,stream>>>(h, ln2_g + l*DD, ln2_b + l*DD, hn);
    gemm_dma<2><<<dim3(ROWS/128, FFD/128),256,0,stream>>>(
        hn, f1T + (size_t)l*FFD*DD, ff1_b + (size_t)l*FFD, ffb, ROWS, FFD, DD);
    gemm_dma_n64<<<dim3(ROWS/128, DD/64),256,0,stream>>>(
        ffb, f2T + (size_t)l*DD*FFD, ff2_b + (size_t)l*DD, h, ROWS, DD, FFD);
  }
  ln_kernel<<<ROWS/4,256,0,stream>>>(h, lnf_g, lnf_b, hn);
  gemm_small<64,64><<<dim3(ROWS/64, VV/64),256,0,stream>>>(
      hn, lmT, (float*)d_out, ROWS, VV, DD);
}